// Round 30
// baseline (110.886 us; speedup 1.0000x reference)
//
#include <hip/hip_runtime.h>
#include <math.h>

#define N_    8
#define C_    256
#define H_    64
#define W_    64
#define HW    4096
#define OUT_  256
#define HEADS 8
#define HD    32
#define K2    9
#define OFFCH 144   // HEADS*K2*2
#define AWCH  72    // HEADS*K2
#define KTOT  2304  // 9 taps * 256 c
#define WPROWS 256  // Wp rows (216 real + zero pad to 256)
#define ABASE 16896 // bf16 offset of B region in conv smem (2*4*66*32)

typedef __bf16 bf16x8 __attribute__((ext_vector_type(8)));
typedef __bf16 bf16x4 __attribute__((ext_vector_type(4)));
typedef float  f32x4  __attribute__((ext_vector_type(4)));

__device__ __forceinline__ void gload_lds16(const void* g, void* l) {
  __builtin_amdgcn_global_load_lds(
      (const __attribute__((address_space(1))) void*)g,
      (__attribute__((address_space(3))) void*)l, 16, 0, 0);
}

// ---------------------------------------------------------------------------
// conv body R26 (measured-best): R21 sync schedule + dxp-major tap order for
// A-fragment reuse. Issue index s = dxp*3+dy; tap t = dy*3+dxp.
// ---------------------------------------------------------------------------
__device__ __forceinline__ void conv_body(
    __bf16* smem, const __bf16* __restrict__ xp, const __bf16* __restrict__ Wp,
    const float* __restrict__ biasp, const __bf16* __restrict__ zbuf,
    __bf16* __restrict__ P2, int yt, int bn, int n, int tid)
{
  const int y0 = yt << 1;
  const int lw = tid & 63, wv = tid >> 6;
  const int lr = lw & 15, lg = lw >> 4;

  f32x4 acc[8][2];
#pragma unroll
  for (int m = 0; m < 8; ++m)
#pragma unroll
    for (int nt = 0; nt < 2; ++nt) acc[m][nt] = (f32x4){0.f, 0.f, 0.f, 0.f};

  if (tid < 64) {
    int p = tid & 3, cs = (tid >> 2) & 1, r = (tid >> 3) & 3, buf = tid >> 5;
    int col = cs ? 65 : 0;
    *(uint4*)&smem[((buf * 4 + r) * 66 + col) * 32 + p * 8] =
        make_uint4(0u, 0u, 0u, 0u);
  }

  int aoff[3][4];
#pragma unroll
  for (int d = 0; d < 3; ++d)
#pragma unroll
    for (int mm = 0; mm < 4; ++mm) {
      int col = (mm << 4) + lr + d;
      int p = lg ^ ((col >> 1) & 3);
      aoff[d][mm] = col * 32 + p * 8;
    }
  int boff[2];
#pragma unroll
  for (int nt = 0; nt < 2; ++nt) {
    int col = (nt << 4) + lr;
    int p = lg ^ ((col >> 1) & 3);
    boff[nt] = ABASE + wv * 3072 + col * 32 + p * 8;
  }

  const int scg = lw & 3;
  const __bf16* gB[2];
#pragma unroll
  for (int jj = 0; jj < 2; ++jj) {
    int col = (jj << 4) + (lw >> 2);
    int cg = scg ^ ((col >> 1) & 3);
    gB[jj] = Wp + (size_t)(bn * 128 + wv * 32 + col) * KTOT + (cg << 3);
  }
  const __bf16* gA[4];
  int aAdd;
  {
    int y = y0 - 1 + wv;
    bool valid = ((unsigned)y < (unsigned)H_);
    aAdd = valid ? 1 : 0;
#pragma unroll
    for (int k = 0; k < 4; ++k) {
      int col = 1 + (k << 4) + (lw >> 2);
      int cg = scg ^ ((col >> 1) & 3);
      gA[k] = valid
          ? xp + ((size_t)(n * HW) + y * W_ + (col - 1)) * C_ + (cg << 3)
          : zbuf;
    }
  }

  auto stageB = [&](int elemOff, int pbuf) {
#pragma unroll
    for (int jj = 0; jj < 2; ++jj)
      gload_lds16(gB[jj] + elemOff,
                  &smem[ABASE + wv * 3072 + pbuf * 1024 + (jj << 9)]);
  };
  auto stageA = [&](int c0elem, int buf) {
    const int add = aAdd ? c0elem : 0;
#pragma unroll
    for (int k = 0; k < 4; ++k)
      gload_lds16(gA[k] + add,
                  &smem[((buf * 4 + wv) * 66 + 1 + (k << 4)) * 32]);
  };

  stageA(0, 0);
  stageB(0 * C_ + 0, 0);
  stageB(3 * C_ + 0, 1);
  asm volatile("s_waitcnt vmcnt(4)" ::: "memory");
  __builtin_amdgcn_s_barrier();
  asm volatile("" ::: "memory");

  for (int cc = 0; cc < 4; ++cc) {
    const bool lastcc = (cc == 3);
#pragma unroll
    for (int sub = 0; sub < 2; ++sub) {
      const int ci = (cc << 1) + sub;
      const int abuf = sub;
      bf16x8 a[8];
#pragma unroll
      for (int s = 0; s < 9; ++s) {
        const int dxp = s / 3, dy = s % 3;
        const int pbR = s % 3;
        const int pbW = (s + 2) % 3;
        const bool lastSlice = lastcc && (sub == 1);

        if (s == 1 && ci < 7) stageA((ci + 1) << 5, sub ^ 1);

        if (!(lastSlice && s >= 7)) {
          const int sn  = (s + 2 < 9) ? (s + 2) : (s - 7);
          const int cin = (s + 2 < 9) ? ci : (ci + 1);
          const int tn  = (sn % 3) * 3 + (sn / 3);
          stageB(tn * C_ + (cin << 5), pbW);
        }

        if (lastSlice && s == 8)
          asm volatile("s_waitcnt vmcnt(0)" ::: "memory");
        else if (lastSlice && s == 7)
          asm volatile("s_waitcnt vmcnt(2)" ::: "memory");
        else if ((s == 1 || s == 2) && ci < 7)
          asm volatile("s_waitcnt vmcnt(8)" ::: "memory");
        else
          asm volatile("s_waitcnt vmcnt(4)" ::: "memory");

        if (dy == 0) {
#pragma unroll
          for (int m = 0; m < 8; ++m) {
            const int rr = (m >> 2);
            a[m] = *(const bf16x8*)&smem[aoff[dxp][m & 3] +
                                         (abuf * 4 + rr) * 2112];
          }
        } else {
#pragma unroll
          for (int m = 0; m < 4; ++m) a[m] = a[m + 4];
#pragma unroll
          for (int m = 4; m < 8; ++m) {
            const int rr = 1 + dy;
            a[m] = *(const bf16x8*)&smem[aoff[dxp][m & 3] +
                                         (abuf * 4 + rr) * 2112];
          }
        }
        bf16x8 b[2];
#pragma unroll
        for (int nt = 0; nt < 2; ++nt)
          b[nt] = *(const bf16x8*)&smem[boff[nt] + (pbR << 10)];

        __builtin_amdgcn_s_setprio(1);
#pragma unroll
        for (int m = 0; m < 8; ++m)
#pragma unroll
          for (int nt = 0; nt < 2; ++nt)
            acc[m][nt] = __builtin_amdgcn_mfma_f32_16x16x32_bf16(
                a[m], b[nt], acc[m][nt], 0, 0, 0);
        __builtin_amdgcn_s_setprio(0);

        if (s == 8 && !lastSlice) {
          __builtin_amdgcn_s_barrier();
          asm volatile("" ::: "memory");
        }
      }
    }
  }

#pragma unroll
  for (int nt = 0; nt < 2; ++nt) {
    const int co = bn * 128 + wv * 32 + (nt << 4) + lr;
    if (co < 216) {
      const float bias = biasp[co];
      int idx;
      if (co < OFFCH) {
        int hh = co / 18;
        idx = (hh << 5) + (co - 18 * hh);
      } else {
        int r = co - OFFCH;
        int hh = r / 9;
        idx = (hh << 5) + 18 + (r - 9 * hh);
      }
#pragma unroll
      for (int m = 0; m < 8; ++m) {
#pragma unroll
        for (int reg = 0; reg < 4; ++reg) {
          const int sl = (m << 4) + (lg << 2) + reg;
          const int yout = y0 + (sl >> 6), xo = sl & 63;
          float v = acc[m][nt][reg] + bias;
          if (co >= OFFCH) v = 1.f / (1.f + expf(-v));
          P2[((size_t)n * HW + yout * W_ + xo) * 256 + idx] = (__bf16)v;
        }
      }
    }
  }
}

// ---------------------------------------------------------------------------
// gemm body (R22 pipeline): 3 rotating buf pairs, counted vmcnt, setprio.
// ---------------------------------------------------------------------------
template <int MODE>
__device__ __forceinline__ void gemm_body(
    __bf16* smem, const __bf16* __restrict__ A, const __bf16* __restrict__ Wb,
    __bf16* __restrict__ out_b, float* __restrict__ out_f,
    int st, int bn, int n, int tid)
{
  const int s0 = st << 7;
  const int lw = tid & 63, wv = tid >> 6;
  const int lr = lw & 15, lg = lw >> 4;
  const int sm_base = wv << 5;

  f32x4 acc[2][8];
#pragma unroll
  for (int m = 0; m < 2; ++m)
#pragma unroll
    for (int nt = 0; nt < 8; ++nt) acc[m][nt] = (f32x4){0.f, 0.f, 0.f, 0.f};

  int aoff[2];
#pragma unroll
  for (int m = 0; m < 2; ++m) {
    int row = sm_base + (m << 4) + lr;
    int p = lg ^ ((row >> 1) & 3);
    aoff[m] = row * 32 + p * 8;
  }
  int boff[8];
#pragma unroll
  for (int nt = 0; nt < 8; ++nt) {
    int row = (nt << 4) + lr;
    int p = lg ^ ((row >> 1) & 3);
    boff[nt] = 12288 + row * 32 + p * 8;
  }

  const __bf16* gA[2];
  const __bf16* gB[2];
#pragma unroll
  for (int jj = 0; jj < 2; ++jj) {
    int j = wv * 2 + jj;
    int row = (j << 4) + (lw >> 2);
    int cg = (lw & 3) ^ ((row >> 1) & 3);
    gA[jj] = A + ((size_t)n * HW + s0 + row) * 256 + (cg << 3);
    gB[jj] = Wb + ((size_t)((bn << 7) + row)) * 256 + (cg << 3);
  }

  auto stage = [&](int k, int buf) {
    const int koff = k << 5;
#pragma unroll
    for (int jj = 0; jj < 2; ++jj)
      gload_lds16(gA[jj] + koff, &smem[buf * 4096 + ((wv * 2 + jj) << 9)]);
#pragma unroll
    for (int jj = 0; jj < 2; ++jj)
      gload_lds16(gB[jj] + koff,
                  &smem[12288 + buf * 4096 + ((wv * 2 + jj) << 9)]);
  };

  stage(0, 0);
  stage(1, 1);

#pragma unroll
  for (int k = 0; k < 8; ++k) {
    if (k < 7)
      asm volatile("s_waitcnt vmcnt(4)" ::: "memory");
    else
      asm volatile("s_waitcnt vmcnt(0)" ::: "memory");
    __builtin_amdgcn_s_barrier();
    asm volatile("" ::: "memory");

    if (k + 2 < 8) stage(k + 2, (k + 2) % 3);

    const int buf = k % 3;
    bf16x8 a[2], b[8];
#pragma unroll
    for (int m = 0; m < 2; ++m)
      a[m] = *(const bf16x8*)&smem[aoff[m] + buf * 4096];
#pragma unroll
    for (int nt = 0; nt < 8; ++nt)
      b[nt] = *(const bf16x8*)&smem[boff[nt] + buf * 4096];

    __builtin_amdgcn_s_setprio(1);
#pragma unroll
    for (int m = 0; m < 2; ++m)
#pragma unroll
      for (int nt = 0; nt < 8; ++nt)
        acc[m][nt] = __builtin_amdgcn_mfma_f32_16x16x32_bf16(
            a[m], b[nt], acc[m][nt], 0, 0, 0);
    __builtin_amdgcn_s_setprio(0);
  }

#pragma unroll
  for (int m = 0; m < 2; ++m) {
#pragma unroll
    for (int nt = 0; nt < 8; ++nt) {
      const int co = (bn << 7) + (nt << 4) + lr;
      if (MODE == 0) {
#pragma unroll
        for (int reg = 0; reg < 4; ++reg) {
          const int sm = sm_base + (m << 4) + (lg << 2) + reg;
          out_b[((size_t)n * HW + s0 + sm) * 256 + co] = (__bf16)acc[m][nt][reg];
        }
      } else {
        const int sm = sm_base + (m << 4) + (lg << 2);
        float4 v4 = make_float4(acc[m][nt][0], acc[m][nt][1],
                                acc[m][nt][2], acc[m][nt][3]);
        *(float4*)&out_f[((size_t)(n * 256 + co)) * HW + s0 + sm] = v4;
      }
    }
  }
}

// ---------------------------------------------------------------------------
// fused_pre: pack_x (blocks 0..2047) + pack_all (blocks 2048..2815).
// ---------------------------------------------------------------------------
__global__ __launch_bounds__(256) void fused_pre_kernel(
    const float* __restrict__ x, __bf16* __restrict__ xp,
    const float* __restrict__ off_w, const float* __restrict__ off_b,
    const float* __restrict__ attn_w, const float* __restrict__ attn_b,
    const float* __restrict__ Wv, const float* __restrict__ Wo,
    __bf16* __restrict__ Wp, float* __restrict__ biasp,
    __bf16* __restrict__ zbuf, __bf16* __restrict__ Wvb,
    __bf16* __restrict__ Wob)
{
  const int b = blockIdx.x;
  const int tid = threadIdx.x;
  __shared__ float tile[64][65];

  if (b < 2048) {
    const int c0 = (b & 3) << 6;
    const int y  = (b >> 2) & 63;
    const int n  = b >> 8;
    const int tx = tid & 63, tg = tid >> 6;
#pragma unroll
    for (int i = 0; i < 16; ++i) {
      int cl = tg + (i << 2);
      tile[cl][tx] = x[((size_t)(n * C_ + c0 + cl) * H_ + y) * W_ + tx];
    }
    __syncthreads();
#pragma unroll
    for (int i = 0; i < 16; ++i) {
      int xl = tg + (i << 2);
      xp[((size_t)(n * HW) + y * W_ + xl) * C_ + c0 + tx] = (__bf16)tile[tx][xl];
    }
  } else {
    const int bb = b - 2048;
    const int c = tid;
    if (bb < 256) {
      const int co = bb;
      if (co == 0) {
        *(uint4*)&zbuf[(size_t)c * 8] = make_uint4(0u, 0u, 0u, 0u);
      }
      const float* base = nullptr;
      if (co < OFFCH)      base = off_w  + ((size_t)co * C_ + c) * 9;
      else if (co < 216)   base = attn_w + ((size_t)(co - OFFCH) * C_ + c) * 9;
#pragma unroll
      for (int t = 0; t < 9; ++t) {
        float w = base ? base[t] : 0.f;
        Wp[(size_t)co * KTOT + t * C_ + c] = (__bf16)w;
      }
      if (c == 0) {
        float bv = 0.f;
        if (co < OFFCH) bv = off_b[co];
        else if (co < 216) bv = attn_b[co - OFFCH];
        biasp[co] = bv;
      }
    } else if (bb < 512) {
      const int i = (bb - 256) * 256 + c;
      Wvb[i] = (__bf16)Wv[i];
    } else {
      const int i = (bb - 512) * 256 + c;
      Wob[i] = (__bf16)Wo[i];
    }
  }
}

// ---------------------------------------------------------------------------
// fused_cv: conv (bn 0..1) co-dispatched with vproj gemm (bn 2..3).
// ---------------------------------------------------------------------------
__global__ __launch_bounds__(256) void fused_cv_kernel(
    const __bf16* __restrict__ xp, const __bf16* __restrict__ Wp,
    const float* __restrict__ biasp, const __bf16* __restrict__ zbuf,
    __bf16* __restrict__ P2, const __bf16* __restrict__ Wvb,
    __bf16* __restrict__ vtb)
{
  __shared__ __align__(16) __bf16 smem[16896 + 12288];
  const int bn = blockIdx.y;
  if (bn < 2)
    conv_body(smem, xp, Wp, biasp, zbuf, P2, blockIdx.x, bn, blockIdx.z,
              threadIdx.x);
  else
    gemm_body<0>(smem, xp, Wvb, vtb, nullptr, blockIdx.x, bn - 2, blockIdx.z,
                 threadIdx.x);
}

// ---------------------------------------------------------------------------
// wo projection (standalone; depends on sample output).
// ---------------------------------------------------------------------------
__global__ __launch_bounds__(256) void wo_kernel(
    const __bf16* __restrict__ comb, const __bf16* __restrict__ Wob,
    float* __restrict__ out)
{
  __shared__ __align__(16) __bf16 smem[24576];
  gemm_body<1>(smem, comb, Wob, nullptr, out, blockIdx.x, blockIdx.y,
               blockIdx.z, threadIdx.x);
}

// ---------------------------------------------------------------------------
// Deformable sampling R30: 4 query rows per block (11-row / 44 KB window,
// staging per query row 2.75 rows), 1 lane per point x 32 ch (weight math
// duplication eliminated). Exact global fallback for out-of-window corners.
// ---------------------------------------------------------------------------
__global__ __launch_bounds__(256) void sample_kernel(
    const __bf16* __restrict__ vtb, const __bf16* __restrict__ P2,
    __bf16* __restrict__ comb)
{
  const int b  = blockIdx.x;           // (n*8 + h)*16 + y4
  const int y4 = b & 15;
  const int h  = (b >> 4) & 7;
  const int n  = b >> 7;
  const int yb = y4 << 2;              // query rows yb..yb+3
  const int tid = threadIdx.x;
  const int yloc = tid >> 6, xq = tid & 63;
  const int y = yb + yloc;
  const int wv = tid >> 6;

  __shared__ __align__(16) __bf16 vsl[11 * 64 * 32];   // rows yb-3..yb+7, 44 KB

  // ---- stage 11 window rows (wave-uniform LDS base + lane-linear dst) ----
  const int xs = tid >> 2, cs = tid & 3;
  const __bf16* vsrc =
      vtb + ((size_t)n * HW) * 256 + (h << 5) + (cs << 3) + (size_t)xs * 256;
#pragma unroll
  for (int r = 0; r < 11; ++r) {
    int yy = yb - 3 + r;
    if ((unsigned)yy < (unsigned)H_)
      gload_lds16(vsrc + (size_t)yy * (64 * 256),
                  &vsl[(r * 64 + (wv << 4)) * 32]);
  }

  const __bf16* prow = P2 + ((size_t)n * HW + y * 64 + xq) * 256 + (h << 5);
  bf16x8 p0 = *(const bf16x8*)(prow);
  bf16x8 p1 = *(const bf16x8*)(prow + 8);
  bf16x8 p2 = *(const bf16x8*)(prow + 16);
  bf16x4 p3 = *(const bf16x4*)(prow + 24);

  __syncthreads();                               // drains vmcnt (gload_lds)

  float acc[32];
#pragma unroll
  for (int j = 0; j < 32; ++j) acc[j] = 0.f;

  const __bf16* vbase = vtb + ((size_t)n * HW) * 256 + (h << 5);

#pragma unroll
  for (int k = 0; k < K2; ++k) {
    float offx, offy, a;
    if (k < 4)      { offx = (float)p0[2 * k];       offy = (float)p0[2 * k + 1]; }
    else if (k < 8) { offx = (float)p1[2 * (k - 4)]; offy = (float)p1[2 * (k - 4) + 1]; }
    else            { offx = (float)p2[0];           offy = (float)p2[1]; }
    if (k < 6)      a = (float)p2[2 + k];
    else            a = (float)p3[k - 6];

    const float xpf = (float)xq + offx * (63.f / 64.f);
    const float ypf = (float)y  + offy * (63.f / 64.f);
    const float fx0 = floorf(xpf), fy0 = floorf(ypf);
    const int ix0 = (int)fx0, iy0 = (int)fy0;
    const float wx1 = xpf - fx0, wx0 = 1.f - wx1;
    const float wy1 = ypf - fy0, wy0 = 1.f - wy1;

#pragma unroll
    for (int cy = 0; cy < 2; ++cy) {
      const int yi = iy0 + cy;
      if ((unsigned)yi >= (unsigned)H_) continue;
      const float wy = cy ? wy1 : wy0;
      const int ridx = yi - (yb - 3);
#pragma unroll
      for (int cx = 0; cx < 2; ++cx) {
        const int xi = ix0 + cx;
        if ((unsigned)xi >= (unsigned)W_) continue;
        const float cw = a * wy * (cx ? wx1 : wx0);
        bf16x8 v0, v1, v2, v3;
        if ((unsigned)ridx < 11u) {              // in-window: LDS
          const __bf16* lp = &vsl[(ridx * 64 + xi) * 32];
          v0 = *(const bf16x8*)lp;
          v1 = *(const bf16x8*)(lp + 8);
          v2 = *(const bf16x8*)(lp + 16);
          v3 = *(const bf16x8*)(lp + 24);
        } else {                                 // rare escape: global
          const __bf16* gp = vbase + (size_t)(yi * W_ + xi) * 256;
          v0 = *(const bf16x8*)gp;
          v1 = *(const bf16x8*)(gp + 8);
          v2 = *(const bf16x8*)(gp + 16);
          v3 = *(const bf16x8*)(gp + 24);
        }
#pragma unroll
        for (int j = 0; j < 8; ++j) {
          acc[j]      = fmaf(cw, (float)v0[j], acc[j]);
          acc[8 + j]  = fmaf(cw, (float)v1[j], acc[8 + j]);
          acc[16 + j] = fmaf(cw, (float)v2[j], acc[16 + j]);
          acc[24 + j] = fmaf(cw, (float)v3[j], acc[24 + j]);
        }
      }
    }
  }

  bf16x8 r0, r1, r2, r3;
#pragma unroll
  for (int j = 0; j < 8; ++j) {
    r0[j] = (__bf16)acc[j];
    r1[j] = (__bf16)acc[8 + j];
    r2[j] = (__bf16)acc[16 + j];
    r3[j] = (__bf16)acc[24 + j];
  }
  __bf16* crow = comb + ((size_t)n * HW + y * 64 + xq) * 256 + (h << 5);
  *(bf16x8*)crow = r0;
  *(bf16x8*)(crow + 8) = r1;
  *(bf16x8*)(crow + 16) = r2;
  *(bf16x8*)(crow + 24) = r3;
}

// ---------------------------------------------------------------------------
extern "C" void kernel_launch(void* const* d_in, const int* in_sizes, int n_in,
                              void* d_out, int out_size, void* d_ws,
                              size_t ws_size, hipStream_t stream)
{
  const float* x      = (const float*)d_in[0];
  // d_in[1] = Wq, d_in[2] = Wk : dead code (q,k unused in reference)
  const float* Wv     = (const float*)d_in[3];
  const float* off_w  = (const float*)d_in[4];
  const float* off_b  = (const float*)d_in[5];
  const float* attn_w = (const float*)d_in[6];
  const float* attn_b = (const float*)d_in[7];
  const float* Wo     = (const float*)d_in[8];
  float* out = (float*)d_out;

  __bf16* vtb   = (__bf16*)d_ws;                         // 16.78 MB
  __bf16* xp    = vtb + (size_t)N_ * HW * OUT_;          // 16.78 MB
  __bf16* comb  = xp + (size_t)N_ * HW * C_;             // 16.78 MB
  __bf16* P2    = comb + (size_t)N_ * HW * OUT_;         // 16.78 MB (head-packed)
  __bf16* Wp    = P2 + (size_t)N_ * HW * 256;            //  1.18 MB (256 rows)
  __bf16* Wvb   = Wp + (size_t)WPROWS * KTOT;            //  128 KB
  __bf16* Wob   = Wvb + (size_t)OUT_ * C_;               //  128 KB
  __bf16* zbuf  = Wob + (size_t)OUT_ * OUT_;             //  4 KB zero page
  float*  biasp = (float*)(zbuf + 2048);                 //  1 KB

  fused_pre_kernel<<<dim3(2816), 256, 0, stream>>>(
      x, xp, off_w, off_b, attn_w, attn_b, Wv, Wo, Wp, biasp, zbuf, Wvb, Wob);
  fused_cv_kernel<<<dim3(32, 4, N_), 256, 0, stream>>>(xp, Wp, biasp, zbuf, P2,
                                                       Wvb, vtb);
  sample_kernel<<<dim3(N_ * HEADS * 16), 256, 0, stream>>>(vtb, P2, comb);
  wo_kernel<<<dim3(32, 2, N_), 256, 0, stream>>>(comb, Wob, out);
}

// Round 31
// 106.984 us; speedup vs baseline: 1.0365x; 1.0365x over previous
//
#include <hip/hip_runtime.h>
#include <math.h>

#define N_    8
#define C_    256
#define H_    64
#define W_    64
#define HW    4096
#define OUT_  256
#define HEADS 8
#define HD    32
#define K2    9
#define OFFCH 144   // HEADS*K2*2
#define AWCH  72    // HEADS*K2
#define KTOT  2304  // 9 taps * 256 c
#define WPROWS 256  // Wp rows (216 real + zero pad to 256)
#define ABASE 16896 // bf16 offset of B region in conv smem (2*4*66*32)

typedef __bf16 bf16x8 __attribute__((ext_vector_type(8)));
typedef __bf16 bf16x4 __attribute__((ext_vector_type(4)));
typedef float  f32x4  __attribute__((ext_vector_type(4)));

__device__ __forceinline__ void gload_lds16(const void* g, void* l) {
  __builtin_amdgcn_global_load_lds(
      (const __attribute__((address_space(1))) void*)g,
      (__attribute__((address_space(3))) void*)l, 16, 0, 0);
}

// ---------------------------------------------------------------------------
// conv body R26 (measured-best): R21 sync schedule + dxp-major tap order for
// A-fragment reuse. Issue index s = dxp*3+dy; tap t = dy*3+dxp.
// ---------------------------------------------------------------------------
__device__ __forceinline__ void conv_body(
    __bf16* smem, const __bf16* __restrict__ xp, const __bf16* __restrict__ Wp,
    const float* __restrict__ biasp, const __bf16* __restrict__ zbuf,
    __bf16* __restrict__ P2, int yt, int bn, int n, int tid)
{
  const int y0 = yt << 1;
  const int lw = tid & 63, wv = tid >> 6;
  const int lr = lw & 15, lg = lw >> 4;

  f32x4 acc[8][2];
#pragma unroll
  for (int m = 0; m < 8; ++m)
#pragma unroll
    for (int nt = 0; nt < 2; ++nt) acc[m][nt] = (f32x4){0.f, 0.f, 0.f, 0.f};

  if (tid < 64) {
    int p = tid & 3, cs = (tid >> 2) & 1, r = (tid >> 3) & 3, buf = tid >> 5;
    int col = cs ? 65 : 0;
    *(uint4*)&smem[((buf * 4 + r) * 66 + col) * 32 + p * 8] =
        make_uint4(0u, 0u, 0u, 0u);
  }

  int aoff[3][4];
#pragma unroll
  for (int d = 0; d < 3; ++d)
#pragma unroll
    for (int mm = 0; mm < 4; ++mm) {
      int col = (mm << 4) + lr + d;
      int p = lg ^ ((col >> 1) & 3);
      aoff[d][mm] = col * 32 + p * 8;
    }
  int boff[2];
#pragma unroll
  for (int nt = 0; nt < 2; ++nt) {
    int col = (nt << 4) + lr;
    int p = lg ^ ((col >> 1) & 3);
    boff[nt] = ABASE + wv * 3072 + col * 32 + p * 8;
  }

  const int scg = lw & 3;
  const __bf16* gB[2];
#pragma unroll
  for (int jj = 0; jj < 2; ++jj) {
    int col = (jj << 4) + (lw >> 2);
    int cg = scg ^ ((col >> 1) & 3);
    gB[jj] = Wp + (size_t)(bn * 128 + wv * 32 + col) * KTOT + (cg << 3);
  }
  const __bf16* gA[4];
  int aAdd;
  {
    int y = y0 - 1 + wv;
    bool valid = ((unsigned)y < (unsigned)H_);
    aAdd = valid ? 1 : 0;
#pragma unroll
    for (int k = 0; k < 4; ++k) {
      int col = 1 + (k << 4) + (lw >> 2);
      int cg = scg ^ ((col >> 1) & 3);
      gA[k] = valid
          ? xp + ((size_t)(n * HW) + y * W_ + (col - 1)) * C_ + (cg << 3)
          : zbuf;
    }
  }

  auto stageB = [&](int elemOff, int pbuf) {
#pragma unroll
    for (int jj = 0; jj < 2; ++jj)
      gload_lds16(gB[jj] + elemOff,
                  &smem[ABASE + wv * 3072 + pbuf * 1024 + (jj << 9)]);
  };
  auto stageA = [&](int c0elem, int buf) {
    const int add = aAdd ? c0elem : 0;
#pragma unroll
    for (int k = 0; k < 4; ++k)
      gload_lds16(gA[k] + add,
                  &smem[((buf * 4 + wv) * 66 + 1 + (k << 4)) * 32]);
  };

  stageA(0, 0);
  stageB(0 * C_ + 0, 0);
  stageB(3 * C_ + 0, 1);
  asm volatile("s_waitcnt vmcnt(4)" ::: "memory");
  __builtin_amdgcn_s_barrier();
  asm volatile("" ::: "memory");

  for (int cc = 0; cc < 4; ++cc) {
    const bool lastcc = (cc == 3);
#pragma unroll
    for (int sub = 0; sub < 2; ++sub) {
      const int ci = (cc << 1) + sub;
      const int abuf = sub;
      bf16x8 a[8];
#pragma unroll
      for (int s = 0; s < 9; ++s) {
        const int dxp = s / 3, dy = s % 3;
        const int pbR = s % 3;
        const int pbW = (s + 2) % 3;
        const bool lastSlice = lastcc && (sub == 1);

        if (s == 1 && ci < 7) stageA((ci + 1) << 5, sub ^ 1);

        if (!(lastSlice && s >= 7)) {
          const int sn  = (s + 2 < 9) ? (s + 2) : (s - 7);
          const int cin = (s + 2 < 9) ? ci : (ci + 1);
          const int tn  = (sn % 3) * 3 + (sn / 3);
          stageB(tn * C_ + (cin << 5), pbW);
        }

        if (lastSlice && s == 8)
          asm volatile("s_waitcnt vmcnt(0)" ::: "memory");
        else if (lastSlice && s == 7)
          asm volatile("s_waitcnt vmcnt(2)" ::: "memory");
        else if ((s == 1 || s == 2) && ci < 7)
          asm volatile("s_waitcnt vmcnt(8)" ::: "memory");
        else
          asm volatile("s_waitcnt vmcnt(4)" ::: "memory");

        if (dy == 0) {
#pragma unroll
          for (int m = 0; m < 8; ++m) {
            const int rr = (m >> 2);
            a[m] = *(const bf16x8*)&smem[aoff[dxp][m & 3] +
                                         (abuf * 4 + rr) * 2112];
          }
        } else {
#pragma unroll
          for (int m = 0; m < 4; ++m) a[m] = a[m + 4];
#pragma unroll
          for (int m = 4; m < 8; ++m) {
            const int rr = 1 + dy;
            a[m] = *(const bf16x8*)&smem[aoff[dxp][m & 3] +
                                         (abuf * 4 + rr) * 2112];
          }
        }
        bf16x8 b[2];
#pragma unroll
        for (int nt = 0; nt < 2; ++nt)
          b[nt] = *(const bf16x8*)&smem[boff[nt] + (pbR << 10)];

        __builtin_amdgcn_s_setprio(1);
#pragma unroll
        for (int m = 0; m < 8; ++m)
#pragma unroll
          for (int nt = 0; nt < 2; ++nt)
            acc[m][nt] = __builtin_amdgcn_mfma_f32_16x16x32_bf16(
                a[m], b[nt], acc[m][nt], 0, 0, 0);
        __builtin_amdgcn_s_setprio(0);

        if (s == 8 && !lastSlice) {
          __builtin_amdgcn_s_barrier();
          asm volatile("" ::: "memory");
        }
      }
    }
  }

#pragma unroll
  for (int nt = 0; nt < 2; ++nt) {
    const int co = bn * 128 + wv * 32 + (nt << 4) + lr;
    if (co < 216) {
      const float bias = biasp[co];
      int idx;
      if (co < OFFCH) {
        int hh = co / 18;
        idx = (hh << 5) + (co - 18 * hh);
      } else {
        int r = co - OFFCH;
        int hh = r / 9;
        idx = (hh << 5) + 18 + (r - 9 * hh);
      }
#pragma unroll
      for (int m = 0; m < 8; ++m) {
#pragma unroll
        for (int reg = 0; reg < 4; ++reg) {
          const int sl = (m << 4) + (lg << 2) + reg;
          const int yout = y0 + (sl >> 6), xo = sl & 63;
          float v = acc[m][nt][reg] + bias;
          if (co >= OFFCH) v = 1.f / (1.f + expf(-v));
          P2[((size_t)n * HW + yout * W_ + xo) * 256 + idx] = (__bf16)v;
        }
      }
    }
  }
}

// ---------------------------------------------------------------------------
// gemm body (R22 pipeline): 3 rotating buf pairs, counted vmcnt, setprio.
// ---------------------------------------------------------------------------
template <int MODE>
__device__ __forceinline__ void gemm_body(
    __bf16* smem, const __bf16* __restrict__ A, const __bf16* __restrict__ Wb,
    __bf16* __restrict__ out_b, float* __restrict__ out_f,
    int st, int bn, int n, int tid)
{
  const int s0 = st << 7;
  const int lw = tid & 63, wv = tid >> 6;
  const int lr = lw & 15, lg = lw >> 4;
  const int sm_base = wv << 5;

  f32x4 acc[2][8];
#pragma unroll
  for (int m = 0; m < 2; ++m)
#pragma unroll
    for (int nt = 0; nt < 8; ++nt) acc[m][nt] = (f32x4){0.f, 0.f, 0.f, 0.f};

  int aoff[2];
#pragma unroll
  for (int m = 0; m < 2; ++m) {
    int row = sm_base + (m << 4) + lr;
    int p = lg ^ ((row >> 1) & 3);
    aoff[m] = row * 32 + p * 8;
  }
  int boff[8];
#pragma unroll
  for (int nt = 0; nt < 8; ++nt) {
    int row = (nt << 4) + lr;
    int p = lg ^ ((row >> 1) & 3);
    boff[nt] = 12288 + row * 32 + p * 8;
  }

  const __bf16* gA[2];
  const __bf16* gB[2];
#pragma unroll
  for (int jj = 0; jj < 2; ++jj) {
    int j = wv * 2 + jj;
    int row = (j << 4) + (lw >> 2);
    int cg = (lw & 3) ^ ((row >> 1) & 3);
    gA[jj] = A + ((size_t)n * HW + s0 + row) * 256 + (cg << 3);
    gB[jj] = Wb + ((size_t)((bn << 7) + row)) * 256 + (cg << 3);
  }

  auto stage = [&](int k, int buf) {
    const int koff = k << 5;
#pragma unroll
    for (int jj = 0; jj < 2; ++jj)
      gload_lds16(gA[jj] + koff, &smem[buf * 4096 + ((wv * 2 + jj) << 9)]);
#pragma unroll
    for (int jj = 0; jj < 2; ++jj)
      gload_lds16(gB[jj] + koff,
                  &smem[12288 + buf * 4096 + ((wv * 2 + jj) << 9)]);
  };

  stage(0, 0);
  stage(1, 1);

#pragma unroll
  for (int k = 0; k < 8; ++k) {
    if (k < 7)
      asm volatile("s_waitcnt vmcnt(4)" ::: "memory");
    else
      asm volatile("s_waitcnt vmcnt(0)" ::: "memory");
    __builtin_amdgcn_s_barrier();
    asm volatile("" ::: "memory");

    if (k + 2 < 8) stage(k + 2, (k + 2) % 3);

    const int buf = k % 3;
    bf16x8 a[2], b[8];
#pragma unroll
    for (int m = 0; m < 2; ++m)
      a[m] = *(const bf16x8*)&smem[aoff[m] + buf * 4096];
#pragma unroll
    for (int nt = 0; nt < 8; ++nt)
      b[nt] = *(const bf16x8*)&smem[boff[nt] + buf * 4096];

    __builtin_amdgcn_s_setprio(1);
#pragma unroll
    for (int m = 0; m < 2; ++m)
#pragma unroll
      for (int nt = 0; nt < 8; ++nt)
        acc[m][nt] = __builtin_amdgcn_mfma_f32_16x16x32_bf16(
            a[m], b[nt], acc[m][nt], 0, 0, 0);
    __builtin_amdgcn_s_setprio(0);
  }

#pragma unroll
  for (int m = 0; m < 2; ++m) {
#pragma unroll
    for (int nt = 0; nt < 8; ++nt) {
      const int co = (bn << 7) + (nt << 4) + lr;
      if (MODE == 0) {
#pragma unroll
        for (int reg = 0; reg < 4; ++reg) {
          const int sm = sm_base + (m << 4) + (lg << 2) + reg;
          out_b[((size_t)n * HW + s0 + sm) * 256 + co] = (__bf16)acc[m][nt][reg];
        }
      } else {
        const int sm = sm_base + (m << 4) + (lg << 2);
        float4 v4 = make_float4(acc[m][nt][0], acc[m][nt][1],
                                acc[m][nt][2], acc[m][nt][3]);
        *(float4*)&out_f[((size_t)(n * 256 + co)) * HW + s0 + sm] = v4;
      }
    }
  }
}

// ---------------------------------------------------------------------------
// fused_pre: pack_x (blocks 0..2047) + pack_all (blocks 2048..2815).
// ---------------------------------------------------------------------------
__global__ __launch_bounds__(256) void fused_pre_kernel(
    const float* __restrict__ x, __bf16* __restrict__ xp,
    const float* __restrict__ off_w, const float* __restrict__ off_b,
    const float* __restrict__ attn_w, const float* __restrict__ attn_b,
    const float* __restrict__ Wv, const float* __restrict__ Wo,
    __bf16* __restrict__ Wp, float* __restrict__ biasp,
    __bf16* __restrict__ zbuf, __bf16* __restrict__ Wvb,
    __bf16* __restrict__ Wob)
{
  const int b = blockIdx.x;
  const int tid = threadIdx.x;
  __shared__ float tile[64][65];

  if (b < 2048) {
    const int c0 = (b & 3) << 6;
    const int y  = (b >> 2) & 63;
    const int n  = b >> 8;
    const int tx = tid & 63, tg = tid >> 6;
#pragma unroll
    for (int i = 0; i < 16; ++i) {
      int cl = tg + (i << 2);
      tile[cl][tx] = x[((size_t)(n * C_ + c0 + cl) * H_ + y) * W_ + tx];
    }
    __syncthreads();
#pragma unroll
    for (int i = 0; i < 16; ++i) {
      int xl = tg + (i << 2);
      xp[((size_t)(n * HW) + y * W_ + xl) * C_ + c0 + tx] = (__bf16)tile[tx][xl];
    }
  } else {
    const int bb = b - 2048;
    const int c = tid;
    if (bb < 256) {
      const int co = bb;
      if (co == 0) {
        *(uint4*)&zbuf[(size_t)c * 8] = make_uint4(0u, 0u, 0u, 0u);
      }
      const float* base = nullptr;
      if (co < OFFCH)      base = off_w  + ((size_t)co * C_ + c) * 9;
      else if (co < 216)   base = attn_w + ((size_t)(co - OFFCH) * C_ + c) * 9;
#pragma unroll
      for (int t = 0; t < 9; ++t) {
        float w = base ? base[t] : 0.f;
        Wp[(size_t)co * KTOT + t * C_ + c] = (__bf16)w;
      }
      if (c == 0) {
        float bv = 0.f;
        if (co < OFFCH) bv = off_b[co];
        else if (co < 216) bv = attn_b[co - OFFCH];
        biasp[co] = bv;
      }
    } else if (bb < 512) {
      const int i = (bb - 256) * 256 + c;
      Wvb[i] = (__bf16)Wv[i];
    } else {
      const int i = (bb - 512) * 256 + c;
      Wob[i] = (__bf16)Wo[i];
    }
  }
}

// ---------------------------------------------------------------------------
// fused_cv: conv (bn 0..1) co-dispatched with vproj gemm (bn 2..3).
// ---------------------------------------------------------------------------
__global__ __launch_bounds__(256) void fused_cv_kernel(
    const __bf16* __restrict__ xp, const __bf16* __restrict__ Wp,
    const float* __restrict__ biasp, const __bf16* __restrict__ zbuf,
    __bf16* __restrict__ P2, const __bf16* __restrict__ Wvb,
    __bf16* __restrict__ vtb)
{
  __shared__ __align__(16) __bf16 smem[16896 + 12288];
  const int bn = blockIdx.y;
  if (bn < 2)
    conv_body(smem, xp, Wp, biasp, zbuf, P2, blockIdx.x, bn, blockIdx.z,
              threadIdx.x);
  else
    gemm_body<0>(smem, xp, Wvb, vtb, nullptr, blockIdx.x, bn - 2, blockIdx.z,
                 threadIdx.x);
}

// ---------------------------------------------------------------------------
// wo projection (standalone; depends on sample output).
// ---------------------------------------------------------------------------
__global__ __launch_bounds__(256) void wo_kernel(
    const __bf16* __restrict__ comb, const __bf16* __restrict__ Wob,
    float* __restrict__ out)
{
  __shared__ __align__(16) __bf16 smem[24576];
  gemm_body<1>(smem, comb, Wob, nullptr, out, blockIdx.x, blockIdx.y,
               blockIdx.z, threadIdx.x);
}

// ---------------------------------------------------------------------------
// Deformable sampling R29 (measured-best): 2 query rows per block (9-row /
// 36 KB window, staging per query row 4.5 rows), 2 lanes per point x 16 ch.
// Exact global fallback for out-of-window corners.
// ---------------------------------------------------------------------------
__global__ __launch_bounds__(256) void sample_kernel(
    const __bf16* __restrict__ vtb, const __bf16* __restrict__ P2,
    __bf16* __restrict__ comb)
{
  const int b  = blockIdx.x;           // (n*8 + h)*32 + ypair
  const int yp = b & 31;
  const int h  = (b >> 5) & 7;
  const int n  = b >> 8;
  const int yb = yp << 1;              // query rows yb, yb+1
  const int tid = threadIdx.x;
  const int cg  = tid & 1;             // 16-channel half
  const int pt  = tid >> 1;            // 0..127
  const int yloc = pt >> 6, xq = pt & 63;
  const int y = yb + yloc;
  const int wv = tid >> 6;

  __shared__ __align__(16) __bf16 vsl[9 * 64 * 32];   // rows yb-3..yb+5, 36 KB

  // ---- stage 9 window rows (row index uniform per step) ----
  const int xs = tid >> 2, cs = tid & 3;
  const __bf16* vsrc =
      vtb + ((size_t)n * HW) * 256 + (h << 5) + (cs << 3) + (size_t)xs * 256;
#pragma unroll
  for (int r = 0; r < 9; ++r) {
    int yy = yb - 3 + r;
    if ((unsigned)yy < (unsigned)H_)
      gload_lds16(vsrc + (size_t)yy * (64 * 256),
                  &vsl[(r * 64 + (wv << 4)) * 32]);
  }

  const __bf16* prow = P2 + ((size_t)n * HW + y * 64 + xq) * 256 + (h << 5);
  bf16x8 p0 = *(const bf16x8*)(prow);
  bf16x8 p1 = *(const bf16x8*)(prow + 8);
  bf16x8 p2 = *(const bf16x8*)(prow + 16);
  bf16x4 p3 = *(const bf16x4*)(prow + 24);

  __syncthreads();                               // drains vmcnt (gload_lds)

  float acc[16];
#pragma unroll
  for (int j = 0; j < 16; ++j) acc[j] = 0.f;

  const __bf16* vbase = vtb + ((size_t)n * HW) * 256 + (h << 5) + (cg << 4);

#pragma unroll
  for (int k = 0; k < K2; ++k) {
    float offx, offy, a;
    if (k < 4)      { offx = (float)p0[2 * k];       offy = (float)p0[2 * k + 1]; }
    else if (k < 8) { offx = (float)p1[2 * (k - 4)]; offy = (float)p1[2 * (k - 4) + 1]; }
    else            { offx = (float)p2[0];           offy = (float)p2[1]; }
    if (k < 6)      a = (float)p2[2 + k];
    else            a = (float)p3[k - 6];

    const float xpf = (float)xq + offx * (63.f / 64.f);
    const float ypf = (float)y  + offy * (63.f / 64.f);
    const float fx0 = floorf(xpf), fy0 = floorf(ypf);
    const int ix0 = (int)fx0, iy0 = (int)fy0;
    const float wx1 = xpf - fx0, wx0 = 1.f - wx1;
    const float wy1 = ypf - fy0, wy0 = 1.f - wy1;

#pragma unroll
    for (int cy = 0; cy < 2; ++cy) {
      const int yi = iy0 + cy;
      if ((unsigned)yi >= (unsigned)H_) continue;
      const float wy = cy ? wy1 : wy0;
      const int ridx = yi - (yb - 3);
#pragma unroll
      for (int cx = 0; cx < 2; ++cx) {
        const int xi = ix0 + cx;
        if ((unsigned)xi >= (unsigned)W_) continue;
        const float cw = a * wy * (cx ? wx1 : wx0);
        bf16x8 v0, v1;
        if ((unsigned)ridx < 9u) {               // in-window: LDS
          const __bf16* lp = &vsl[(ridx * 64 + xi) * 32 + (cg << 4)];
          v0 = *(const bf16x8*)lp;
          v1 = *(const bf16x8*)(lp + 8);
        } else {                                 // rare escape: global
          const __bf16* gp = vbase + (size_t)(yi * W_ + xi) * 256;
          v0 = *(const bf16x8*)gp;
          v1 = *(const bf16x8*)(gp + 8);
        }
#pragma unroll
        for (int j = 0; j < 8; ++j) acc[j] = fmaf(cw, (float)v0[j], acc[j]);
#pragma unroll
        for (int j = 0; j < 8; ++j)
          acc[8 + j] = fmaf(cw, (float)v1[j], acc[8 + j]);
      }
    }
  }

  bf16x8 r0, r1;
#pragma unroll
  for (int j = 0; j < 8; ++j) { r0[j] = (__bf16)acc[j]; r1[j] = (__bf16)acc[8 + j]; }
  __bf16* crow = comb + ((size_t)n * HW + y * 64 + xq) * 256 + (h << 5) + (cg << 4);
  *(bf16x8*)crow = r0;
  *(bf16x8*)(crow + 8) = r1;
}

// ---------------------------------------------------------------------------
extern "C" void kernel_launch(void* const* d_in, const int* in_sizes, int n_in,
                              void* d_out, int out_size, void* d_ws,
                              size_t ws_size, hipStream_t stream)
{
  const float* x      = (const float*)d_in[0];
  // d_in[1] = Wq, d_in[2] = Wk : dead code (q,k unused in reference)
  const float* Wv     = (const float*)d_in[3];
  const float* off_w  = (const float*)d_in[4];
  const float* off_b  = (const float*)d_in[5];
  const float* attn_w = (const float*)d_in[6];
  const float* attn_b = (const float*)d_in[7];
  const float* Wo     = (const float*)d_in[8];
  float* out = (float*)d_out;

  __bf16* vtb   = (__bf16*)d_ws;                         // 16.78 MB
  __bf16* xp    = vtb + (size_t)N_ * HW * OUT_;          // 16.78 MB
  __bf16* comb  = xp + (size_t)N_ * HW * C_;             // 16.78 MB
  __bf16* P2    = comb + (size_t)N_ * HW * OUT_;         // 16.78 MB (head-packed)
  __bf16* Wp    = P2 + (size_t)N_ * HW * 256;            //  1.18 MB (256 rows)
  __bf16* Wvb   = Wp + (size_t)WPROWS * KTOT;            //  128 KB
  __bf16* Wob   = Wvb + (size_t)OUT_ * C_;               //  128 KB
  __bf16* zbuf  = Wob + (size_t)OUT_ * OUT_;             //  4 KB zero page
  float*  biasp = (float*)(zbuf + 2048);                 //  1 KB

  fused_pre_kernel<<<dim3(2816), 256, 0, stream>>>(
      x, xp, off_w, off_b, attn_w, attn_b, Wv, Wo, Wp, biasp, zbuf, Wvb, Wob);
  fused_cv_kernel<<<dim3(32, 4, N_), 256, 0, stream>>>(xp, Wp, biasp, zbuf, P2,
                                                       Wvb, vtb);
  sample_kernel<<<dim3(N_ * HEADS * 32), 256, 0, stream>>>(vtb, P2, comb);
  wo_kernel<<<dim3(32, 2, N_), 256, 0, stream>>>(comb, Wob, out);
}

// Round 32
// 105.619 us; speedup vs baseline: 1.0499x; 1.0129x over previous
//
#include <hip/hip_runtime.h>
#include <math.h>

#define N_    8
#define C_    256
#define H_    64
#define W_    64
#define HW    4096
#define OUT_  256
#define HEADS 8
#define HD    32
#define K2    9
#define OFFCH 144   // HEADS*K2*2
#define AWCH  72    // HEADS*K2
#define KTOT  2304  // 9 taps * 256 c
#define WPROWS 256  // Wp rows (216 real + zero pad to 256)
#define ABASE 16896 // bf16 offset of B region in conv smem (2*4*66*32)

typedef __bf16 bf16x8 __attribute__((ext_vector_type(8)));
typedef __bf16 bf16x4 __attribute__((ext_vector_type(4)));
typedef float  f32x4  __attribute__((ext_vector_type(4)));

__device__ __forceinline__ void gload_lds16(const void* g, void* l) {
  __builtin_amdgcn_global_load_lds(
      (const __attribute__((address_space(1))) void*)g,
      (__attribute__((address_space(3))) void*)l, 16, 0, 0);
}

// ---------------------------------------------------------------------------
// conv body R26 (measured-best): R21 sync schedule + dxp-major tap order for
// A-fragment reuse. Issue index s = dxp*3+dy; tap t = dy*3+dxp.
// ---------------------------------------------------------------------------
__device__ __forceinline__ void conv_body(
    __bf16* smem, const __bf16* __restrict__ xp, const __bf16* __restrict__ Wp,
    const float* __restrict__ biasp, const __bf16* __restrict__ zbuf,
    __bf16* __restrict__ P2, int yt, int bn, int n, int tid)
{
  const int y0 = yt << 1;
  const int lw = tid & 63, wv = tid >> 6;
  const int lr = lw & 15, lg = lw >> 4;

  f32x4 acc[8][2];
#pragma unroll
  for (int m = 0; m < 8; ++m)
#pragma unroll
    for (int nt = 0; nt < 2; ++nt) acc[m][nt] = (f32x4){0.f, 0.f, 0.f, 0.f};

  if (tid < 64) {
    int p = tid & 3, cs = (tid >> 2) & 1, r = (tid >> 3) & 3, buf = tid >> 5;
    int col = cs ? 65 : 0;
    *(uint4*)&smem[((buf * 4 + r) * 66 + col) * 32 + p * 8] =
        make_uint4(0u, 0u, 0u, 0u);
  }

  int aoff[3][4];
#pragma unroll
  for (int d = 0; d < 3; ++d)
#pragma unroll
    for (int mm = 0; mm < 4; ++mm) {
      int col = (mm << 4) + lr + d;
      int p = lg ^ ((col >> 1) & 3);
      aoff[d][mm] = col * 32 + p * 8;
    }
  int boff[2];
#pragma unroll
  for (int nt = 0; nt < 2; ++nt) {
    int col = (nt << 4) + lr;
    int p = lg ^ ((col >> 1) & 3);
    boff[nt] = ABASE + wv * 3072 + col * 32 + p * 8;
  }

  const int scg = lw & 3;
  const __bf16* gB[2];
#pragma unroll
  for (int jj = 0; jj < 2; ++jj) {
    int col = (jj << 4) + (lw >> 2);
    int cg = scg ^ ((col >> 1) & 3);
    gB[jj] = Wp + (size_t)(bn * 128 + wv * 32 + col) * KTOT + (cg << 3);
  }
  const __bf16* gA[4];
  int aAdd;
  {
    int y = y0 - 1 + wv;
    bool valid = ((unsigned)y < (unsigned)H_);
    aAdd = valid ? 1 : 0;
#pragma unroll
    for (int k = 0; k < 4; ++k) {
      int col = 1 + (k << 4) + (lw >> 2);
      int cg = scg ^ ((col >> 1) & 3);
      gA[k] = valid
          ? xp + ((size_t)(n * HW) + y * W_ + (col - 1)) * C_ + (cg << 3)
          : zbuf;
    }
  }

  auto stageB = [&](int elemOff, int pbuf) {
#pragma unroll
    for (int jj = 0; jj < 2; ++jj)
      gload_lds16(gB[jj] + elemOff,
                  &smem[ABASE + wv * 3072 + pbuf * 1024 + (jj << 9)]);
  };
  auto stageA = [&](int c0elem, int buf) {
    const int add = aAdd ? c0elem : 0;
#pragma unroll
    for (int k = 0; k < 4; ++k)
      gload_lds16(gA[k] + add,
                  &smem[((buf * 4 + wv) * 66 + 1 + (k << 4)) * 32]);
  };

  stageA(0, 0);
  stageB(0 * C_ + 0, 0);
  stageB(3 * C_ + 0, 1);
  asm volatile("s_waitcnt vmcnt(4)" ::: "memory");
  __builtin_amdgcn_s_barrier();
  asm volatile("" ::: "memory");

  for (int cc = 0; cc < 4; ++cc) {
    const bool lastcc = (cc == 3);
#pragma unroll
    for (int sub = 0; sub < 2; ++sub) {
      const int ci = (cc << 1) + sub;
      const int abuf = sub;
      bf16x8 a[8];
#pragma unroll
      for (int s = 0; s < 9; ++s) {
        const int dxp = s / 3, dy = s % 3;
        const int pbR = s % 3;
        const int pbW = (s + 2) % 3;
        const bool lastSlice = lastcc && (sub == 1);

        if (s == 1 && ci < 7) stageA((ci + 1) << 5, sub ^ 1);

        if (!(lastSlice && s >= 7)) {
          const int sn  = (s + 2 < 9) ? (s + 2) : (s - 7);
          const int cin = (s + 2 < 9) ? ci : (ci + 1);
          const int tn  = (sn % 3) * 3 + (sn / 3);
          stageB(tn * C_ + (cin << 5), pbW);
        }

        if (lastSlice && s == 8)
          asm volatile("s_waitcnt vmcnt(0)" ::: "memory");
        else if (lastSlice && s == 7)
          asm volatile("s_waitcnt vmcnt(2)" ::: "memory");
        else if ((s == 1 || s == 2) && ci < 7)
          asm volatile("s_waitcnt vmcnt(8)" ::: "memory");
        else
          asm volatile("s_waitcnt vmcnt(4)" ::: "memory");

        if (dy == 0) {
#pragma unroll
          for (int m = 0; m < 8; ++m) {
            const int rr = (m >> 2);
            a[m] = *(const bf16x8*)&smem[aoff[dxp][m & 3] +
                                         (abuf * 4 + rr) * 2112];
          }
        } else {
#pragma unroll
          for (int m = 0; m < 4; ++m) a[m] = a[m + 4];
#pragma unroll
          for (int m = 4; m < 8; ++m) {
            const int rr = 1 + dy;
            a[m] = *(const bf16x8*)&smem[aoff[dxp][m & 3] +
                                         (abuf * 4 + rr) * 2112];
          }
        }
        bf16x8 b[2];
#pragma unroll
        for (int nt = 0; nt < 2; ++nt)
          b[nt] = *(const bf16x8*)&smem[boff[nt] + (pbR << 10)];

        __builtin_amdgcn_s_setprio(1);
#pragma unroll
        for (int m = 0; m < 8; ++m)
#pragma unroll
          for (int nt = 0; nt < 2; ++nt)
            acc[m][nt] = __builtin_amdgcn_mfma_f32_16x16x32_bf16(
                a[m], b[nt], acc[m][nt], 0, 0, 0);
        __builtin_amdgcn_s_setprio(0);

        if (s == 8 && !lastSlice) {
          __builtin_amdgcn_s_barrier();
          asm volatile("" ::: "memory");
        }
      }
    }
  }

#pragma unroll
  for (int nt = 0; nt < 2; ++nt) {
    const int co = bn * 128 + wv * 32 + (nt << 4) + lr;
    if (co < 216) {
      const float bias = biasp[co];
      int idx;
      if (co < OFFCH) {
        int hh = co / 18;
        idx = (hh << 5) + (co - 18 * hh);
      } else {
        int r = co - OFFCH;
        int hh = r / 9;
        idx = (hh << 5) + 18 + (r - 9 * hh);
      }
#pragma unroll
      for (int m = 0; m < 8; ++m) {
#pragma unroll
        for (int reg = 0; reg < 4; ++reg) {
          const int sl = (m << 4) + (lg << 2) + reg;
          const int yout = y0 + (sl >> 6), xo = sl & 63;
          float v = acc[m][nt][reg] + bias;
          if (co >= OFFCH) v = 1.f / (1.f + expf(-v));
          P2[((size_t)n * HW + yout * W_ + xo) * 256 + idx] = (__bf16)v;
        }
      }
    }
  }
}

// ---------------------------------------------------------------------------
// gemm body (R22 pipeline): 3 rotating buf pairs, counted vmcnt, setprio.
// ---------------------------------------------------------------------------
template <int MODE>
__device__ __forceinline__ void gemm_body(
    __bf16* smem, const __bf16* __restrict__ A, const __bf16* __restrict__ Wb,
    __bf16* __restrict__ out_b, float* __restrict__ out_f,
    int st, int bn, int n, int tid)
{
  const int s0 = st << 7;
  const int lw = tid & 63, wv = tid >> 6;
  const int lr = lw & 15, lg = lw >> 4;
  const int sm_base = wv << 5;

  f32x4 acc[2][8];
#pragma unroll
  for (int m = 0; m < 2; ++m)
#pragma unroll
    for (int nt = 0; nt < 8; ++nt) acc[m][nt] = (f32x4){0.f, 0.f, 0.f, 0.f};

  int aoff[2];
#pragma unroll
  for (int m = 0; m < 2; ++m) {
    int row = sm_base + (m << 4) + lr;
    int p = lg ^ ((row >> 1) & 3);
    aoff[m] = row * 32 + p * 8;
  }
  int boff[8];
#pragma unroll
  for (int nt = 0; nt < 8; ++nt) {
    int row = (nt << 4) + lr;
    int p = lg ^ ((row >> 1) & 3);
    boff[nt] = 12288 + row * 32 + p * 8;
  }

  const __bf16* gA[2];
  const __bf16* gB[2];
#pragma unroll
  for (int jj = 0; jj < 2; ++jj) {
    int j = wv * 2 + jj;
    int row = (j << 4) + (lw >> 2);
    int cg = (lw & 3) ^ ((row >> 1) & 3);
    gA[jj] = A + ((size_t)n * HW + s0 + row) * 256 + (cg << 3);
    gB[jj] = Wb + ((size_t)((bn << 7) + row)) * 256 + (cg << 3);
  }

  auto stage = [&](int k, int buf) {
    const int koff = k << 5;
#pragma unroll
    for (int jj = 0; jj < 2; ++jj)
      gload_lds16(gA[jj] + koff, &smem[buf * 4096 + ((wv * 2 + jj) << 9)]);
#pragma unroll
    for (int jj = 0; jj < 2; ++jj)
      gload_lds16(gB[jj] + koff,
                  &smem[12288 + buf * 4096 + ((wv * 2 + jj) << 9)]);
  };

  stage(0, 0);
  stage(1, 1);

#pragma unroll
  for (int k = 0; k < 8; ++k) {
    if (k < 7)
      asm volatile("s_waitcnt vmcnt(4)" ::: "memory");
    else
      asm volatile("s_waitcnt vmcnt(0)" ::: "memory");
    __builtin_amdgcn_s_barrier();
    asm volatile("" ::: "memory");

    if (k + 2 < 8) stage(k + 2, (k + 2) % 3);

    const int buf = k % 3;
    bf16x8 a[2], b[8];
#pragma unroll
    for (int m = 0; m < 2; ++m)
      a[m] = *(const bf16x8*)&smem[aoff[m] + buf * 4096];
#pragma unroll
    for (int nt = 0; nt < 8; ++nt)
      b[nt] = *(const bf16x8*)&smem[boff[nt] + buf * 4096];

    __builtin_amdgcn_s_setprio(1);
#pragma unroll
    for (int m = 0; m < 2; ++m)
#pragma unroll
      for (int nt = 0; nt < 8; ++nt)
        acc[m][nt] = __builtin_amdgcn_mfma_f32_16x16x32_bf16(
            a[m], b[nt], acc[m][nt], 0, 0, 0);
    __builtin_amdgcn_s_setprio(0);
  }

#pragma unroll
  for (int m = 0; m < 2; ++m) {
#pragma unroll
    for (int nt = 0; nt < 8; ++nt) {
      const int co = (bn << 7) + (nt << 4) + lr;
      if (MODE == 0) {
#pragma unroll
        for (int reg = 0; reg < 4; ++reg) {
          const int sm = sm_base + (m << 4) + (lg << 2) + reg;
          out_b[((size_t)n * HW + s0 + sm) * 256 + co] = (__bf16)acc[m][nt][reg];
        }
      } else {
        const int sm = sm_base + (m << 4) + (lg << 2);
        float4 v4 = make_float4(acc[m][nt][0], acc[m][nt][1],
                                acc[m][nt][2], acc[m][nt][3]);
        *(float4*)&out_f[((size_t)(n * 256 + co)) * HW + s0 + sm] = v4;
      }
    }
  }
}

// ---------------------------------------------------------------------------
// fused_pre: pack_x (blocks 0..2047) + pack_all (blocks 2048..2815).
// ---------------------------------------------------------------------------
__global__ __launch_bounds__(256) void fused_pre_kernel(
    const float* __restrict__ x, __bf16* __restrict__ xp,
    const float* __restrict__ off_w, const float* __restrict__ off_b,
    const float* __restrict__ attn_w, const float* __restrict__ attn_b,
    const float* __restrict__ Wv, const float* __restrict__ Wo,
    __bf16* __restrict__ Wp, float* __restrict__ biasp,
    __bf16* __restrict__ zbuf, __bf16* __restrict__ Wvb,
    __bf16* __restrict__ Wob)
{
  const int b = blockIdx.x;
  const int tid = threadIdx.x;
  __shared__ float tile[64][65];

  if (b < 2048) {
    const int c0 = (b & 3) << 6;
    const int y  = (b >> 2) & 63;
    const int n  = b >> 8;
    const int tx = tid & 63, tg = tid >> 6;
#pragma unroll
    for (int i = 0; i < 16; ++i) {
      int cl = tg + (i << 2);
      tile[cl][tx] = x[((size_t)(n * C_ + c0 + cl) * H_ + y) * W_ + tx];
    }
    __syncthreads();
#pragma unroll
    for (int i = 0; i < 16; ++i) {
      int xl = tg + (i << 2);
      xp[((size_t)(n * HW) + y * W_ + xl) * C_ + c0 + tx] = (__bf16)tile[tx][xl];
    }
  } else {
    const int bb = b - 2048;
    const int c = tid;
    if (bb < 256) {
      const int co = bb;
      if (co == 0) {
        *(uint4*)&zbuf[(size_t)c * 8] = make_uint4(0u, 0u, 0u, 0u);
      }
      const float* base = nullptr;
      if (co < OFFCH)      base = off_w  + ((size_t)co * C_ + c) * 9;
      else if (co < 216)   base = attn_w + ((size_t)(co - OFFCH) * C_ + c) * 9;
#pragma unroll
      for (int t = 0; t < 9; ++t) {
        float w = base ? base[t] : 0.f;
        Wp[(size_t)co * KTOT + t * C_ + c] = (__bf16)w;
      }
      if (c == 0) {
        float bv = 0.f;
        if (co < OFFCH) bv = off_b[co];
        else if (co < 216) bv = attn_b[co - OFFCH];
        biasp[co] = bv;
      }
    } else if (bb < 512) {
      const int i = (bb - 256) * 256 + c;
      Wvb[i] = (__bf16)Wv[i];
    } else {
      const int i = (bb - 512) * 256 + c;
      Wob[i] = (__bf16)Wo[i];
    }
  }
}

// ---------------------------------------------------------------------------
// fused_cv: conv (bn 0..1) co-dispatched with vproj gemm (bn 2..3).
// ---------------------------------------------------------------------------
__global__ __launch_bounds__(256) void fused_cv_kernel(
    const __bf16* __restrict__ xp, const __bf16* __restrict__ Wp,
    const float* __restrict__ biasp, const __bf16* __restrict__ zbuf,
    __bf16* __restrict__ P2, const __bf16* __restrict__ Wvb,
    __bf16* __restrict__ vtb)
{
  __shared__ __align__(16) __bf16 smem[16896 + 12288];
  const int bn = blockIdx.y;
  if (bn < 2)
    conv_body(smem, xp, Wp, biasp, zbuf, P2, blockIdx.x, bn, blockIdx.z,
              threadIdx.x);
  else
    gemm_body<0>(smem, xp, Wvb, vtb, nullptr, blockIdx.x, bn - 2, blockIdx.z,
                 threadIdx.x);
}

// ---------------------------------------------------------------------------
// wo projection (standalone; depends on sample output).
// ---------------------------------------------------------------------------
__global__ __launch_bounds__(256) void wo_kernel(
    const __bf16* __restrict__ comb, const __bf16* __restrict__ Wob,
    float* __restrict__ out)
{
  __shared__ __align__(16) __bf16 smem[24576];
  gemm_body<1>(smem, comb, Wob, nullptr, out, blockIdx.x, blockIdx.y,
               blockIdx.z, threadIdx.x);
}

// ---------------------------------------------------------------------------
// Deformable sampling R32: 4 query rows per block at 512 threads.
// Window rows yb-3..yb+7 (11 rows, 44 KB) staged by 8 waves in row pairs;
// lanes/point kept at the bracketed optimum of 2 (x 16 ch). Staging per
// query row 4.5 -> 2.75 rows. Exact global fallback for out-of-window.
// ---------------------------------------------------------------------------
__global__ __launch_bounds__(512) void sample_kernel(
    const __bf16* __restrict__ vtb, const __bf16* __restrict__ P2,
    __bf16* __restrict__ comb)
{
  const int b  = blockIdx.x;           // (n*8 + h)*16 + y4
  const int y4 = b & 15;
  const int h  = (b >> 4) & 7;
  const int n  = b >> 7;
  const int yb = y4 << 2;              // query rows yb..yb+3
  const int tid = threadIdx.x;
  const int cg  = tid & 1;             // 16-channel half
  const int pt  = tid >> 1;            // 0..255
  const int yloc = pt >> 6, xq = pt & 63;
  const int y = yb + yloc;
  const int wv = tid >> 6;             // 0..7

  __shared__ __align__(16) __bf16 vsl[11 * 64 * 32];   // rows yb-3..yb+7, 44 KB

  // ---- stage 11 window rows: 8 waves, rows in pairs r = 2*step + (wv>>2) --
  const int xs = ((wv & 3) << 4) + ((tid & 63) >> 2);
  const int cs = tid & 3;
  const __bf16* vsrc =
      vtb + ((size_t)n * HW) * 256 + (h << 5) + (cs << 3) + (size_t)xs * 256;
#pragma unroll
  for (int step = 0; step < 6; ++step) {
    int r = step * 2 + (wv >> 2);      // wave-uniform
    if (r < 11) {
      int yy = yb - 3 + r;
      if ((unsigned)yy < (unsigned)H_)
        gload_lds16(vsrc + (size_t)yy * (64 * 256),
                    &vsl[(r * 64 + ((wv & 3) << 4)) * 32]);
    }
  }

  const __bf16* prow = P2 + ((size_t)n * HW + y * 64 + xq) * 256 + (h << 5);
  bf16x8 p0 = *(const bf16x8*)(prow);
  bf16x8 p1 = *(const bf16x8*)(prow + 8);
  bf16x8 p2 = *(const bf16x8*)(prow + 16);
  bf16x4 p3 = *(const bf16x4*)(prow + 24);

  __syncthreads();                               // drains vmcnt (gload_lds)

  float acc[16];
#pragma unroll
  for (int j = 0; j < 16; ++j) acc[j] = 0.f;

  const __bf16* vbase = vtb + ((size_t)n * HW) * 256 + (h << 5) + (cg << 4);

#pragma unroll
  for (int k = 0; k < K2; ++k) {
    float offx, offy, a;
    if (k < 4)      { offx = (float)p0[2 * k];       offy = (float)p0[2 * k + 1]; }
    else if (k < 8) { offx = (float)p1[2 * (k - 4)]; offy = (float)p1[2 * (k - 4) + 1]; }
    else            { offx = (float)p2[0];           offy = (float)p2[1]; }
    if (k < 6)      a = (float)p2[2 + k];
    else            a = (float)p3[k - 6];

    const float xpf = (float)xq + offx * (63.f / 64.f);
    const float ypf = (float)y  + offy * (63.f / 64.f);
    const float fx0 = floorf(xpf), fy0 = floorf(ypf);
    const int ix0 = (int)fx0, iy0 = (int)fy0;
    const float wx1 = xpf - fx0, wx0 = 1.f - wx1;
    const float wy1 = ypf - fy0, wy0 = 1.f - wy1;

#pragma unroll
    for (int cy = 0; cy < 2; ++cy) {
      const int yi = iy0 + cy;
      if ((unsigned)yi >= (unsigned)H_) continue;
      const float wy = cy ? wy1 : wy0;
      const int ridx = yi - (yb - 3);
#pragma unroll
      for (int cx = 0; cx < 2; ++cx) {
        const int xi = ix0 + cx;
        if ((unsigned)xi >= (unsigned)W_) continue;
        const float cw = a * wy * (cx ? wx1 : wx0);
        bf16x8 v0, v1;
        if ((unsigned)ridx < 11u) {              // in-window: LDS
          const __bf16* lp = &vsl[(ridx * 64 + xi) * 32 + (cg << 4)];
          v0 = *(const bf16x8*)lp;
          v1 = *(const bf16x8*)(lp + 8);
        } else {                                 // rare escape: global
          const __bf16* gp = vbase + (size_t)(yi * W_ + xi) * 256;
          v0 = *(const bf16x8*)gp;
          v1 = *(const bf16x8*)(gp + 8);
        }
#pragma unroll
        for (int j = 0; j < 8; ++j) acc[j] = fmaf(cw, (float)v0[j], acc[j]);
#pragma unroll
        for (int j = 0; j < 8; ++j)
          acc[8 + j] = fmaf(cw, (float)v1[j], acc[8 + j]);
      }
    }
  }

  bf16x8 r0, r1;
#pragma unroll
  for (int j = 0; j < 8; ++j) { r0[j] = (__bf16)acc[j]; r1[j] = (__bf16)acc[8 + j]; }
  __bf16* crow = comb + ((size_t)n * HW + y * 64 + xq) * 256 + (h << 5) + (cg << 4);
  *(bf16x8*)crow = r0;
  *(bf16x8*)(crow + 8) = r1;
}

// ---------------------------------------------------------------------------
extern "C" void kernel_launch(void* const* d_in, const int* in_sizes, int n_in,
                              void* d_out, int out_size, void* d_ws,
                              size_t ws_size, hipStream_t stream)
{
  const float* x      = (const float*)d_in[0];
  // d_in[1] = Wq, d_in[2] = Wk : dead code (q,k unused in reference)
  const float* Wv     = (const float*)d_in[3];
  const float* off_w  = (const float*)d_in[4];
  const float* off_b  = (const float*)d_in[5];
  const float* attn_w = (const float*)d_in[6];
  const float* attn_b = (const float*)d_in[7];
  const float* Wo     = (const float*)d_in[8];
  float* out = (float*)d_out;

  __bf16* vtb   = (__bf16*)d_ws;                         // 16.78 MB
  __bf16* xp    = vtb + (size_t)N_ * HW * OUT_;          // 16.78 MB
  __bf16* comb  = xp + (size_t)N_ * HW * C_;             // 16.78 MB
  __bf16* P2    = comb + (size_t)N_ * HW * OUT_;         // 16.78 MB (head-packed)
  __bf16* Wp    = P2 + (size_t)N_ * HW * 256;            //  1.18 MB (256 rows)
  __bf16* Wvb   = Wp + (size_t)WPROWS * KTOT;            //  128 KB
  __bf16* Wob   = Wvb + (size_t)OUT_ * C_;               //  128 KB
  __bf16* zbuf  = Wob + (size_t)OUT_ * OUT_;             //  4 KB zero page
  float*  biasp = (float*)(zbuf + 2048);                 //  1 KB

  fused_pre_kernel<<<dim3(2816), 256, 0, stream>>>(
      x, xp, off_w, off_b, attn_w, attn_b, Wv, Wo, Wp, biasp, zbuf, Wvb, Wob);
  fused_cv_kernel<<<dim3(32, 4, N_), 256, 0, stream>>>(xp, Wp, biasp, zbuf, P2,
                                                       Wvb, vtb);
  sample_kernel<<<dim3(N_ * HEADS * 16), 512, 0, stream>>>(vtb, P2, comb);
  wo_kernel<<<dim3(32, 2, N_), 256, 0, stream>>>(comb, Wob, out);
}

// Round 33
// 105.137 us; speedup vs baseline: 1.0547x; 1.0046x over previous
//
#include <hip/hip_runtime.h>
#include <math.h>

#define N_    8
#define C_    256
#define H_    64
#define W_    64
#define HW    4096
#define OUT_  256
#define HEADS 8
#define HD    32
#define K2    9
#define OFFCH 144   // HEADS*K2*2
#define AWCH  72    // HEADS*K2
#define KTOT  2304  // 9 taps * 256 c
#define WPROWS 256  // Wp rows (216 real + zero pad to 256)
#define ABASE 16896 // bf16 offset of B region in conv smem (2*4*66*32)

typedef __bf16 bf16x8 __attribute__((ext_vector_type(8)));
typedef __bf16 bf16x4 __attribute__((ext_vector_type(4)));
typedef float  f32x4  __attribute__((ext_vector_type(4)));

__device__ __forceinline__ void gload_lds16(const void* g, void* l) {
  __builtin_amdgcn_global_load_lds(
      (const __attribute__((address_space(1))) void*)g,
      (__attribute__((address_space(3))) void*)l, 16, 0, 0);
}

// ---------------------------------------------------------------------------
// conv body R26 (measured-best): R21 sync schedule + dxp-major tap order for
// A-fragment reuse. Issue index s = dxp*3+dy; tap t = dy*3+dxp.
// ---------------------------------------------------------------------------
__device__ __forceinline__ void conv_body(
    __bf16* smem, const __bf16* __restrict__ xp, const __bf16* __restrict__ Wp,
    const float* __restrict__ biasp, const __bf16* __restrict__ zbuf,
    __bf16* __restrict__ P2, int yt, int bn, int n, int tid)
{
  const int y0 = yt << 1;
  const int lw = tid & 63, wv = tid >> 6;
  const int lr = lw & 15, lg = lw >> 4;

  f32x4 acc[8][2];
#pragma unroll
  for (int m = 0; m < 8; ++m)
#pragma unroll
    for (int nt = 0; nt < 2; ++nt) acc[m][nt] = (f32x4){0.f, 0.f, 0.f, 0.f};

  if (tid < 64) {
    int p = tid & 3, cs = (tid >> 2) & 1, r = (tid >> 3) & 3, buf = tid >> 5;
    int col = cs ? 65 : 0;
    *(uint4*)&smem[((buf * 4 + r) * 66 + col) * 32 + p * 8] =
        make_uint4(0u, 0u, 0u, 0u);
  }

  int aoff[3][4];
#pragma unroll
  for (int d = 0; d < 3; ++d)
#pragma unroll
    for (int mm = 0; mm < 4; ++mm) {
      int col = (mm << 4) + lr + d;
      int p = lg ^ ((col >> 1) & 3);
      aoff[d][mm] = col * 32 + p * 8;
    }
  int boff[2];
#pragma unroll
  for (int nt = 0; nt < 2; ++nt) {
    int col = (nt << 4) + lr;
    int p = lg ^ ((col >> 1) & 3);
    boff[nt] = ABASE + wv * 3072 + col * 32 + p * 8;
  }

  const int scg = lw & 3;
  const __bf16* gB[2];
#pragma unroll
  for (int jj = 0; jj < 2; ++jj) {
    int col = (jj << 4) + (lw >> 2);
    int cg = scg ^ ((col >> 1) & 3);
    gB[jj] = Wp + (size_t)(bn * 128 + wv * 32 + col) * KTOT + (cg << 3);
  }
  const __bf16* gA[4];
  int aAdd;
  {
    int y = y0 - 1 + wv;
    bool valid = ((unsigned)y < (unsigned)H_);
    aAdd = valid ? 1 : 0;
#pragma unroll
    for (int k = 0; k < 4; ++k) {
      int col = 1 + (k << 4) + (lw >> 2);
      int cg = scg ^ ((col >> 1) & 3);
      gA[k] = valid
          ? xp + ((size_t)(n * HW) + y * W_ + (col - 1)) * C_ + (cg << 3)
          : zbuf;
    }
  }

  auto stageB = [&](int elemOff, int pbuf) {
#pragma unroll
    for (int jj = 0; jj < 2; ++jj)
      gload_lds16(gB[jj] + elemOff,
                  &smem[ABASE + wv * 3072 + pbuf * 1024 + (jj << 9)]);
  };
  auto stageA = [&](int c0elem, int buf) {
    const int add = aAdd ? c0elem : 0;
#pragma unroll
    for (int k = 0; k < 4; ++k)
      gload_lds16(gA[k] + add,
                  &smem[((buf * 4 + wv) * 66 + 1 + (k << 4)) * 32]);
  };

  stageA(0, 0);
  stageB(0 * C_ + 0, 0);
  stageB(3 * C_ + 0, 1);
  asm volatile("s_waitcnt vmcnt(4)" ::: "memory");
  __builtin_amdgcn_s_barrier();
  asm volatile("" ::: "memory");

  for (int cc = 0; cc < 4; ++cc) {
    const bool lastcc = (cc == 3);
#pragma unroll
    for (int sub = 0; sub < 2; ++sub) {
      const int ci = (cc << 1) + sub;
      const int abuf = sub;
      bf16x8 a[8];
#pragma unroll
      for (int s = 0; s < 9; ++s) {
        const int dxp = s / 3, dy = s % 3;
        const int pbR = s % 3;
        const int pbW = (s + 2) % 3;
        const bool lastSlice = lastcc && (sub == 1);

        if (s == 1 && ci < 7) stageA((ci + 1) << 5, sub ^ 1);

        if (!(lastSlice && s >= 7)) {
          const int sn  = (s + 2 < 9) ? (s + 2) : (s - 7);
          const int cin = (s + 2 < 9) ? ci : (ci + 1);
          const int tn  = (sn % 3) * 3 + (sn / 3);
          stageB(tn * C_ + (cin << 5), pbW);
        }

        if (lastSlice && s == 8)
          asm volatile("s_waitcnt vmcnt(0)" ::: "memory");
        else if (lastSlice && s == 7)
          asm volatile("s_waitcnt vmcnt(2)" ::: "memory");
        else if ((s == 1 || s == 2) && ci < 7)
          asm volatile("s_waitcnt vmcnt(8)" ::: "memory");
        else
          asm volatile("s_waitcnt vmcnt(4)" ::: "memory");

        if (dy == 0) {
#pragma unroll
          for (int m = 0; m < 8; ++m) {
            const int rr = (m >> 2);
            a[m] = *(const bf16x8*)&smem[aoff[dxp][m & 3] +
                                         (abuf * 4 + rr) * 2112];
          }
        } else {
#pragma unroll
          for (int m = 0; m < 4; ++m) a[m] = a[m + 4];
#pragma unroll
          for (int m = 4; m < 8; ++m) {
            const int rr = 1 + dy;
            a[m] = *(const bf16x8*)&smem[aoff[dxp][m & 3] +
                                         (abuf * 4 + rr) * 2112];
          }
        }
        bf16x8 b[2];
#pragma unroll
        for (int nt = 0; nt < 2; ++nt)
          b[nt] = *(const bf16x8*)&smem[boff[nt] + (pbR << 10)];

        __builtin_amdgcn_s_setprio(1);
#pragma unroll
        for (int m = 0; m < 8; ++m)
#pragma unroll
          for (int nt = 0; nt < 2; ++nt)
            acc[m][nt] = __builtin_amdgcn_mfma_f32_16x16x32_bf16(
                a[m], b[nt], acc[m][nt], 0, 0, 0);
        __builtin_amdgcn_s_setprio(0);

        if (s == 8 && !lastSlice) {
          __builtin_amdgcn_s_barrier();
          asm volatile("" ::: "memory");
        }
      }
    }
  }

#pragma unroll
  for (int nt = 0; nt < 2; ++nt) {
    const int co = bn * 128 + wv * 32 + (nt << 4) + lr;
    if (co < 216) {
      const float bias = biasp[co];
      int idx;
      if (co < OFFCH) {
        int hh = co / 18;
        idx = (hh << 5) + (co - 18 * hh);
      } else {
        int r = co - OFFCH;
        int hh = r / 9;
        idx = (hh << 5) + 18 + (r - 9 * hh);
      }
#pragma unroll
      for (int m = 0; m < 8; ++m) {
#pragma unroll
        for (int reg = 0; reg < 4; ++reg) {
          const int sl = (m << 4) + (lg << 2) + reg;
          const int yout = y0 + (sl >> 6), xo = sl & 63;
          float v = acc[m][nt][reg] + bias;
          if (co >= OFFCH) v = 1.f / (1.f + expf(-v));
          P2[((size_t)n * HW + yout * W_ + xo) * 256 + idx] = (__bf16)v;
        }
      }
    }
  }
}

// ---------------------------------------------------------------------------
// gemm body (R22 pipeline): 3 rotating buf pairs, counted vmcnt, setprio.
// ---------------------------------------------------------------------------
template <int MODE>
__device__ __forceinline__ void gemm_body(
    __bf16* smem, const __bf16* __restrict__ A, const __bf16* __restrict__ Wb,
    __bf16* __restrict__ out_b, float* __restrict__ out_f,
    int st, int bn, int n, int tid)
{
  const int s0 = st << 7;
  const int lw = tid & 63, wv = tid >> 6;
  const int lr = lw & 15, lg = lw >> 4;
  const int sm_base = wv << 5;

  f32x4 acc[2][8];
#pragma unroll
  for (int m = 0; m < 2; ++m)
#pragma unroll
    for (int nt = 0; nt < 8; ++nt) acc[m][nt] = (f32x4){0.f, 0.f, 0.f, 0.f};

  int aoff[2];
#pragma unroll
  for (int m = 0; m < 2; ++m) {
    int row = sm_base + (m << 4) + lr;
    int p = lg ^ ((row >> 1) & 3);
    aoff[m] = row * 32 + p * 8;
  }
  int boff[8];
#pragma unroll
  for (int nt = 0; nt < 8; ++nt) {
    int row = (nt << 4) + lr;
    int p = lg ^ ((row >> 1) & 3);
    boff[nt] = 12288 + row * 32 + p * 8;
  }

  const __bf16* gA[2];
  const __bf16* gB[2];
#pragma unroll
  for (int jj = 0; jj < 2; ++jj) {
    int j = wv * 2 + jj;
    int row = (j << 4) + (lw >> 2);
    int cg = (lw & 3) ^ ((row >> 1) & 3);
    gA[jj] = A + ((size_t)n * HW + s0 + row) * 256 + (cg << 3);
    gB[jj] = Wb + ((size_t)((bn << 7) + row)) * 256 + (cg << 3);
  }

  auto stage = [&](int k, int buf) {
    const int koff = k << 5;
#pragma unroll
    for (int jj = 0; jj < 2; ++jj)
      gload_lds16(gA[jj] + koff, &smem[buf * 4096 + ((wv * 2 + jj) << 9)]);
#pragma unroll
    for (int jj = 0; jj < 2; ++jj)
      gload_lds16(gB[jj] + koff,
                  &smem[12288 + buf * 4096 + ((wv * 2 + jj) << 9)]);
  };

  stage(0, 0);
  stage(1, 1);

#pragma unroll
  for (int k = 0; k < 8; ++k) {
    if (k < 7)
      asm volatile("s_waitcnt vmcnt(4)" ::: "memory");
    else
      asm volatile("s_waitcnt vmcnt(0)" ::: "memory");
    __builtin_amdgcn_s_barrier();
    asm volatile("" ::: "memory");

    if (k + 2 < 8) stage(k + 2, (k + 2) % 3);

    const int buf = k % 3;
    bf16x8 a[2], b[8];
#pragma unroll
    for (int m = 0; m < 2; ++m)
      a[m] = *(const bf16x8*)&smem[aoff[m] + buf * 4096];
#pragma unroll
    for (int nt = 0; nt < 8; ++nt)
      b[nt] = *(const bf16x8*)&smem[boff[nt] + buf * 4096];

    __builtin_amdgcn_s_setprio(1);
#pragma unroll
    for (int m = 0; m < 2; ++m)
#pragma unroll
      for (int nt = 0; nt < 8; ++nt)
        acc[m][nt] = __builtin_amdgcn_mfma_f32_16x16x32_bf16(
            a[m], b[nt], acc[m][nt], 0, 0, 0);
    __builtin_amdgcn_s_setprio(0);
  }

#pragma unroll
  for (int m = 0; m < 2; ++m) {
#pragma unroll
    for (int nt = 0; nt < 8; ++nt) {
      const int co = (bn << 7) + (nt << 4) + lr;
      if (MODE == 0) {
#pragma unroll
        for (int reg = 0; reg < 4; ++reg) {
          const int sm = sm_base + (m << 4) + (lg << 2) + reg;
          out_b[((size_t)n * HW + s0 + sm) * 256 + co] = (__bf16)acc[m][nt][reg];
        }
      } else {
        const int sm = sm_base + (m << 4) + (lg << 2);
        float4 v4 = make_float4(acc[m][nt][0], acc[m][nt][1],
                                acc[m][nt][2], acc[m][nt][3]);
        *(float4*)&out_f[((size_t)(n * 256 + co)) * HW + s0 + sm] = v4;
      }
    }
  }
}

// ---------------------------------------------------------------------------
// fused_pre: pack_x (blocks 0..2047) + pack_all (blocks 2048..2815).
// ---------------------------------------------------------------------------
__global__ __launch_bounds__(256) void fused_pre_kernel(
    const float* __restrict__ x, __bf16* __restrict__ xp,
    const float* __restrict__ off_w, const float* __restrict__ off_b,
    const float* __restrict__ attn_w, const float* __restrict__ attn_b,
    const float* __restrict__ Wv, const float* __restrict__ Wo,
    __bf16* __restrict__ Wp, float* __restrict__ biasp,
    __bf16* __restrict__ zbuf, __bf16* __restrict__ Wvb,
    __bf16* __restrict__ Wob)
{
  const int b = blockIdx.x;
  const int tid = threadIdx.x;
  __shared__ float tile[64][65];

  if (b < 2048) {
    const int c0 = (b & 3) << 6;
    const int y  = (b >> 2) & 63;
    const int n  = b >> 8;
    const int tx = tid & 63, tg = tid >> 6;
#pragma unroll
    for (int i = 0; i < 16; ++i) {
      int cl = tg + (i << 2);
      tile[cl][tx] = x[((size_t)(n * C_ + c0 + cl) * H_ + y) * W_ + tx];
    }
    __syncthreads();
#pragma unroll
    for (int i = 0; i < 16; ++i) {
      int xl = tg + (i << 2);
      xp[((size_t)(n * HW) + y * W_ + xl) * C_ + c0 + tx] = (__bf16)tile[tx][xl];
    }
  } else {
    const int bb = b - 2048;
    const int c = tid;
    if (bb < 256) {
      const int co = bb;
      if (co == 0) {
        *(uint4*)&zbuf[(size_t)c * 8] = make_uint4(0u, 0u, 0u, 0u);
      }
      const float* base = nullptr;
      if (co < OFFCH)      base = off_w  + ((size_t)co * C_ + c) * 9;
      else if (co < 216)   base = attn_w + ((size_t)(co - OFFCH) * C_ + c) * 9;
#pragma unroll
      for (int t = 0; t < 9; ++t) {
        float w = base ? base[t] : 0.f;
        Wp[(size_t)co * KTOT + t * C_ + c] = (__bf16)w;
      }
      if (c == 0) {
        float bv = 0.f;
        if (co < OFFCH) bv = off_b[co];
        else if (co < 216) bv = attn_b[co - OFFCH];
        biasp[co] = bv;
      }
    } else if (bb < 512) {
      const int i = (bb - 256) * 256 + c;
      Wvb[i] = (__bf16)Wv[i];
    } else {
      const int i = (bb - 512) * 256 + c;
      Wob[i] = (__bf16)Wo[i];
    }
  }
}

// ---------------------------------------------------------------------------
// fused_cv: conv (bn 0..1) co-dispatched with vproj gemm (bn 2..3).
// ---------------------------------------------------------------------------
__global__ __launch_bounds__(256) void fused_cv_kernel(
    const __bf16* __restrict__ xp, const __bf16* __restrict__ Wp,
    const float* __restrict__ biasp, const __bf16* __restrict__ zbuf,
    __bf16* __restrict__ P2, const __bf16* __restrict__ Wvb,
    __bf16* __restrict__ vtb)
{
  __shared__ __align__(16) __bf16 smem[16896 + 12288];
  const int bn = blockIdx.y;
  if (bn < 2)
    conv_body(smem, xp, Wp, biasp, zbuf, P2, blockIdx.x, bn, blockIdx.z,
              threadIdx.x);
  else
    gemm_body<0>(smem, xp, Wvb, vtb, nullptr, blockIdx.x, bn - 2, blockIdx.z,
                 threadIdx.x);
}

// ---------------------------------------------------------------------------
// wo projection (standalone; depends on sample output).
// ---------------------------------------------------------------------------
__global__ __launch_bounds__(256) void wo_kernel(
    const __bf16* __restrict__ comb, const __bf16* __restrict__ Wob,
    float* __restrict__ out)
{
  __shared__ __align__(16) __bf16 smem[24576];
  gemm_body<1>(smem, comb, Wob, nullptr, out, blockIdx.x, blockIdx.y,
               blockIdx.z, threadIdx.x);
}

// ---------------------------------------------------------------------------
// Deformable sampling R33: 8 query rows per block at 1024 threads.
// Window rows yb-3..yb+11 (15 rows, 60 KB) staged via 64 wave-slots
// (slot = step*16+wv -> row r=slot>>2, x-quarter q=slot&3; wave-uniform).
// Lanes/point = 2 (x 16 ch, bracketed optimum). Staging per query row
// 2.75 -> 1.875 rows. Exact global fallback for out-of-window corners.
// ---------------------------------------------------------------------------
__global__ __launch_bounds__(1024) void sample_kernel(
    const __bf16* __restrict__ vtb, const __bf16* __restrict__ P2,
    __bf16* __restrict__ comb)
{
  const int b  = blockIdx.x;           // (n*8 + h)*8 + y8
  const int y8 = b & 7;
  const int h  = (b >> 3) & 7;
  const int n  = b >> 6;
  const int yb = y8 << 3;              // query rows yb..yb+7
  const int tid = threadIdx.x;
  const int cg  = tid & 1;             // 16-channel half
  const int pt  = tid >> 1;            // 0..511
  const int yloc = pt >> 6, xq = pt & 63;
  const int y = yb + yloc;
  const int wv = tid >> 6;             // 0..15

  __shared__ __align__(16) __bf16 vsl[15 * 64 * 32];   // rows yb-3..yb+11, 60 KB

  // ---- stage 15 window rows: 64 wave-slots over 4 steps ----
  const int lane = tid & 63;
  const int cs = tid & 3;
  const __bf16* vhead = vtb + ((size_t)n * HW) * 256 + (h << 5) + (cs << 3);
#pragma unroll
  for (int step = 0; step < 4; ++step) {
    int slot = step * 16 + wv;         // wave-uniform
    int r = slot >> 2, q = slot & 3;
    if (r < 15) {
      int yy = yb - 3 + r;
      if ((unsigned)yy < (unsigned)H_) {
        int xs = (q << 4) + (lane >> 2);
        gload_lds16(vhead + ((size_t)yy * W_ + xs) * 256,
                    &vsl[(r * 64 + (q << 4)) * 32]);
      }
    }
  }

  const __bf16* prow = P2 + ((size_t)n * HW + y * 64 + xq) * 256 + (h << 5);
  bf16x8 p0 = *(const bf16x8*)(prow);
  bf16x8 p1 = *(const bf16x8*)(prow + 8);
  bf16x8 p2 = *(const bf16x8*)(prow + 16);
  bf16x4 p3 = *(const bf16x4*)(prow + 24);

  __syncthreads();                               // drains vmcnt (gload_lds)

  float acc[16];
#pragma unroll
  for (int j = 0; j < 16; ++j) acc[j] = 0.f;

  const __bf16* vbase = vtb + ((size_t)n * HW) * 256 + (h << 5) + (cg << 4);

#pragma unroll
  for (int k = 0; k < K2; ++k) {
    float offx, offy, a;
    if (k < 4)      { offx = (float)p0[2 * k];       offy = (float)p0[2 * k + 1]; }
    else if (k < 8) { offx = (float)p1[2 * (k - 4)]; offy = (float)p1[2 * (k - 4) + 1]; }
    else            { offx = (float)p2[0];           offy = (float)p2[1]; }
    if (k < 6)      a = (float)p2[2 + k];
    else            a = (float)p3[k - 6];

    const float xpf = (float)xq + offx * (63.f / 64.f);
    const float ypf = (float)y  + offy * (63.f / 64.f);
    const float fx0 = floorf(xpf), fy0 = floorf(ypf);
    const int ix0 = (int)fx0, iy0 = (int)fy0;
    const float wx1 = xpf - fx0, wx0 = 1.f - wx1;
    const float wy1 = ypf - fy0, wy0 = 1.f - wy1;

#pragma unroll
    for (int cy = 0; cy < 2; ++cy) {
      const int yi = iy0 + cy;
      if ((unsigned)yi >= (unsigned)H_) continue;
      const float wy = cy ? wy1 : wy0;
      const int ridx = yi - (yb - 3);
#pragma unroll
      for (int cx = 0; cx < 2; ++cx) {
        const int xi = ix0 + cx;
        if ((unsigned)xi >= (unsigned)W_) continue;
        const float cw = a * wy * (cx ? wx1 : wx0);
        bf16x8 v0, v1;
        if ((unsigned)ridx < 15u) {              // in-window: LDS
          const __bf16* lp = &vsl[(ridx * 64 + xi) * 32 + (cg << 4)];
          v0 = *(const bf16x8*)lp;
          v1 = *(const bf16x8*)(lp + 8);
        } else {                                 // rare escape: global
          const __bf16* gp = vbase + (size_t)(yi * W_ + xi) * 256;
          v0 = *(const bf16x8*)gp;
          v1 = *(const bf16x8*)(gp + 8);
        }
#pragma unroll
        for (int j = 0; j < 8; ++j) acc[j] = fmaf(cw, (float)v0[j], acc[j]);
#pragma unroll
        for (int j = 0; j < 8; ++j)
          acc[8 + j] = fmaf(cw, (float)v1[j], acc[8 + j]);
      }
    }
  }

  bf16x8 r0, r1;
#pragma unroll
  for (int j = 0; j < 8; ++j) { r0[j] = (__bf16)acc[j]; r1[j] = (__bf16)acc[8 + j]; }
  __bf16* crow = comb + ((size_t)n * HW + y * 64 + xq) * 256 + (h << 5) + (cg << 4);
  *(bf16x8*)crow = r0;
  *(bf16x8*)(crow + 8) = r1;
}

// ---------------------------------------------------------------------------
extern "C" void kernel_launch(void* const* d_in, const int* in_sizes, int n_in,
                              void* d_out, int out_size, void* d_ws,
                              size_t ws_size, hipStream_t stream)
{
  const float* x      = (const float*)d_in[0];
  // d_in[1] = Wq, d_in[2] = Wk : dead code (q,k unused in reference)
  const float* Wv     = (const float*)d_in[3];
  const float* off_w  = (const float*)d_in[4];
  const float* off_b  = (const float*)d_in[5];
  const float* attn_w = (const float*)d_in[6];
  const float* attn_b = (const float*)d_in[7];
  const float* Wo     = (const float*)d_in[8];
  float* out = (float*)d_out;

  __bf16* vtb   = (__bf16*)d_ws;                         // 16.78 MB
  __bf16* xp    = vtb + (size_t)N_ * HW * OUT_;          // 16.78 MB
  __bf16* comb  = xp + (size_t)N_ * HW * C_;             // 16.78 MB
  __bf16* P2    = comb + (size_t)N_ * HW * OUT_;         // 16.78 MB (head-packed)
  __bf16* Wp    = P2 + (size_t)N_ * HW * 256;            //  1.18 MB (256 rows)
  __bf16* Wvb   = Wp + (size_t)WPROWS * KTOT;            //  128 KB
  __bf16* Wob   = Wvb + (size_t)OUT_ * C_;               //  128 KB
  __bf16* zbuf  = Wob + (size_t)OUT_ * OUT_;             //  4 KB zero page
  float*  biasp = (float*)(zbuf + 2048);                 //  1 KB

  fused_pre_kernel<<<dim3(2816), 256, 0, stream>>>(
      x, xp, off_w, off_b, attn_w, attn_b, Wv, Wo, Wp, biasp, zbuf, Wvb, Wob);
  fused_cv_kernel<<<dim3(32, 4, N_), 256, 0, stream>>>(xp, Wp, biasp, zbuf, P2,
                                                       Wvb, vtb);
  sample_kernel<<<dim3(N_ * HEADS * 8), 1024, 0, stream>>>(vtb, P2, comb);
  wo_kernel<<<dim3(32, 2, N_), 256, 0, stream>>>(comb, Wob, out);
}

// Round 34
// 105.088 us; speedup vs baseline: 1.0552x; 1.0005x over previous
//
#include <hip/hip_runtime.h>
#include <math.h>

#define N_    8
#define C_    256
#define H_    64
#define W_    64
#define HW    4096
#define OUT_  256
#define HEADS 8
#define HD    32
#define K2    9
#define OFFCH 144   // HEADS*K2*2
#define AWCH  72    // HEADS*K2
#define KTOT  2304  // 9 taps * 256 c
#define WPROWS 256  // Wp rows (216 real + zero pad to 256)
#define ABASE 16896 // bf16 offset of B region in conv smem (2*4*66*32)

typedef __bf16 bf16x8 __attribute__((ext_vector_type(8)));
typedef __bf16 bf16x4 __attribute__((ext_vector_type(4)));
typedef float  f32x4  __attribute__((ext_vector_type(4)));

__device__ __forceinline__ void gload_lds16(const void* g, void* l) {
  __builtin_amdgcn_global_load_lds(
      (const __attribute__((address_space(1))) void*)g,
      (__attribute__((address_space(3))) void*)l, 16, 0, 0);
}

// ---------------------------------------------------------------------------
// conv body R26 (measured-best): R21 sync schedule + dxp-major tap order for
// A-fragment reuse. Issue index s = dxp*3+dy; tap t = dy*3+dxp.
// ---------------------------------------------------------------------------
__device__ __forceinline__ void conv_body(
    __bf16* smem, const __bf16* __restrict__ xp, const __bf16* __restrict__ Wp,
    const float* __restrict__ biasp, const __bf16* __restrict__ zbuf,
    __bf16* __restrict__ P2, int yt, int bn, int n, int tid)
{
  const int y0 = yt << 1;
  const int lw = tid & 63, wv = tid >> 6;
  const int lr = lw & 15, lg = lw >> 4;

  f32x4 acc[8][2];
#pragma unroll
  for (int m = 0; m < 8; ++m)
#pragma unroll
    for (int nt = 0; nt < 2; ++nt) acc[m][nt] = (f32x4){0.f, 0.f, 0.f, 0.f};

  if (tid < 64) {
    int p = tid & 3, cs = (tid >> 2) & 1, r = (tid >> 3) & 3, buf = tid >> 5;
    int col = cs ? 65 : 0;
    *(uint4*)&smem[((buf * 4 + r) * 66 + col) * 32 + p * 8] =
        make_uint4(0u, 0u, 0u, 0u);
  }

  int aoff[3][4];
#pragma unroll
  for (int d = 0; d < 3; ++d)
#pragma unroll
    for (int mm = 0; mm < 4; ++mm) {
      int col = (mm << 4) + lr + d;
      int p = lg ^ ((col >> 1) & 3);
      aoff[d][mm] = col * 32 + p * 8;
    }
  int boff[2];
#pragma unroll
  for (int nt = 0; nt < 2; ++nt) {
    int col = (nt << 4) + lr;
    int p = lg ^ ((col >> 1) & 3);
    boff[nt] = ABASE + wv * 3072 + col * 32 + p * 8;
  }

  const int scg = lw & 3;
  const __bf16* gB[2];
#pragma unroll
  for (int jj = 0; jj < 2; ++jj) {
    int col = (jj << 4) + (lw >> 2);
    int cg = scg ^ ((col >> 1) & 3);
    gB[jj] = Wp + (size_t)(bn * 128 + wv * 32 + col) * KTOT + (cg << 3);
  }
  const __bf16* gA[4];
  int aAdd;
  {
    int y = y0 - 1 + wv;
    bool valid = ((unsigned)y < (unsigned)H_);
    aAdd = valid ? 1 : 0;
#pragma unroll
    for (int k = 0; k < 4; ++k) {
      int col = 1 + (k << 4) + (lw >> 2);
      int cg = scg ^ ((col >> 1) & 3);
      gA[k] = valid
          ? xp + ((size_t)(n * HW) + y * W_ + (col - 1)) * C_ + (cg << 3)
          : zbuf;
    }
  }

  auto stageB = [&](int elemOff, int pbuf) {
#pragma unroll
    for (int jj = 0; jj < 2; ++jj)
      gload_lds16(gB[jj] + elemOff,
                  &smem[ABASE + wv * 3072 + pbuf * 1024 + (jj << 9)]);
  };
  auto stageA = [&](int c0elem, int buf) {
    const int add = aAdd ? c0elem : 0;
#pragma unroll
    for (int k = 0; k < 4; ++k)
      gload_lds16(gA[k] + add,
                  &smem[((buf * 4 + wv) * 66 + 1 + (k << 4)) * 32]);
  };

  stageA(0, 0);
  stageB(0 * C_ + 0, 0);
  stageB(3 * C_ + 0, 1);
  asm volatile("s_waitcnt vmcnt(4)" ::: "memory");
  __builtin_amdgcn_s_barrier();
  asm volatile("" ::: "memory");

  for (int cc = 0; cc < 4; ++cc) {
    const bool lastcc = (cc == 3);
#pragma unroll
    for (int sub = 0; sub < 2; ++sub) {
      const int ci = (cc << 1) + sub;
      const int abuf = sub;
      bf16x8 a[8];
#pragma unroll
      for (int s = 0; s < 9; ++s) {
        const int dxp = s / 3, dy = s % 3;
        const int pbR = s % 3;
        const int pbW = (s + 2) % 3;
        const bool lastSlice = lastcc && (sub == 1);

        if (s == 1 && ci < 7) stageA((ci + 1) << 5, sub ^ 1);

        if (!(lastSlice && s >= 7)) {
          const int sn  = (s + 2 < 9) ? (s + 2) : (s - 7);
          const int cin = (s + 2 < 9) ? ci : (ci + 1);
          const int tn  = (sn % 3) * 3 + (sn / 3);
          stageB(tn * C_ + (cin << 5), pbW);
        }

        if (lastSlice && s == 8)
          asm volatile("s_waitcnt vmcnt(0)" ::: "memory");
        else if (lastSlice && s == 7)
          asm volatile("s_waitcnt vmcnt(2)" ::: "memory");
        else if ((s == 1 || s == 2) && ci < 7)
          asm volatile("s_waitcnt vmcnt(8)" ::: "memory");
        else
          asm volatile("s_waitcnt vmcnt(4)" ::: "memory");

        if (dy == 0) {
#pragma unroll
          for (int m = 0; m < 8; ++m) {
            const int rr = (m >> 2);
            a[m] = *(const bf16x8*)&smem[aoff[dxp][m & 3] +
                                         (abuf * 4 + rr) * 2112];
          }
        } else {
#pragma unroll
          for (int m = 0; m < 4; ++m) a[m] = a[m + 4];
#pragma unroll
          for (int m = 4; m < 8; ++m) {
            const int rr = 1 + dy;
            a[m] = *(const bf16x8*)&smem[aoff[dxp][m & 3] +
                                         (abuf * 4 + rr) * 2112];
          }
        }
        bf16x8 b[2];
#pragma unroll
        for (int nt = 0; nt < 2; ++nt)
          b[nt] = *(const bf16x8*)&smem[boff[nt] + (pbR << 10)];

        __builtin_amdgcn_s_setprio(1);
#pragma unroll
        for (int m = 0; m < 8; ++m)
#pragma unroll
          for (int nt = 0; nt < 2; ++nt)
            acc[m][nt] = __builtin_amdgcn_mfma_f32_16x16x32_bf16(
                a[m], b[nt], acc[m][nt], 0, 0, 0);
        __builtin_amdgcn_s_setprio(0);

        if (s == 8 && !lastSlice) {
          __builtin_amdgcn_s_barrier();
          asm volatile("" ::: "memory");
        }
      }
    }
  }

#pragma unroll
  for (int nt = 0; nt < 2; ++nt) {
    const int co = bn * 128 + wv * 32 + (nt << 4) + lr;
    if (co < 216) {
      const float bias = biasp[co];
      int idx;
      if (co < OFFCH) {
        int hh = co / 18;
        idx = (hh << 5) + (co - 18 * hh);
      } else {
        int r = co - OFFCH;
        int hh = r / 9;
        idx = (hh << 5) + 18 + (r - 9 * hh);
      }
#pragma unroll
      for (int m = 0; m < 8; ++m) {
#pragma unroll
        for (int reg = 0; reg < 4; ++reg) {
          const int sl = (m << 4) + (lg << 2) + reg;
          const int yout = y0 + (sl >> 6), xo = sl & 63;
          float v = acc[m][nt][reg] + bias;
          if (co >= OFFCH) v = 1.f / (1.f + expf(-v));
          P2[((size_t)n * HW + yout * W_ + xo) * 256 + idx] = (__bf16)v;
        }
      }
    }
  }
}

// ---------------------------------------------------------------------------
// gemm body (R22 pipeline): 3 rotating buf pairs, counted vmcnt, setprio.
// ---------------------------------------------------------------------------
template <int MODE>
__device__ __forceinline__ void gemm_body(
    __bf16* smem, const __bf16* __restrict__ A, const __bf16* __restrict__ Wb,
    __bf16* __restrict__ out_b, float* __restrict__ out_f,
    int st, int bn, int n, int tid)
{
  const int s0 = st << 7;
  const int lw = tid & 63, wv = tid >> 6;
  const int lr = lw & 15, lg = lw >> 4;
  const int sm_base = wv << 5;

  f32x4 acc[2][8];
#pragma unroll
  for (int m = 0; m < 2; ++m)
#pragma unroll
    for (int nt = 0; nt < 8; ++nt) acc[m][nt] = (f32x4){0.f, 0.f, 0.f, 0.f};

  int aoff[2];
#pragma unroll
  for (int m = 0; m < 2; ++m) {
    int row = sm_base + (m << 4) + lr;
    int p = lg ^ ((row >> 1) & 3);
    aoff[m] = row * 32 + p * 8;
  }
  int boff[8];
#pragma unroll
  for (int nt = 0; nt < 8; ++nt) {
    int row = (nt << 4) + lr;
    int p = lg ^ ((row >> 1) & 3);
    boff[nt] = 12288 + row * 32 + p * 8;
  }

  const __bf16* gA[2];
  const __bf16* gB[2];
#pragma unroll
  for (int jj = 0; jj < 2; ++jj) {
    int j = wv * 2 + jj;
    int row = (j << 4) + (lw >> 2);
    int cg = (lw & 3) ^ ((row >> 1) & 3);
    gA[jj] = A + ((size_t)n * HW + s0 + row) * 256 + (cg << 3);
    gB[jj] = Wb + ((size_t)((bn << 7) + row)) * 256 + (cg << 3);
  }

  auto stage = [&](int k, int buf) {
    const int koff = k << 5;
#pragma unroll
    for (int jj = 0; jj < 2; ++jj)
      gload_lds16(gA[jj] + koff, &smem[buf * 4096 + ((wv * 2 + jj) << 9)]);
#pragma unroll
    for (int jj = 0; jj < 2; ++jj)
      gload_lds16(gB[jj] + koff,
                  &smem[12288 + buf * 4096 + ((wv * 2 + jj) << 9)]);
  };

  stage(0, 0);
  stage(1, 1);

#pragma unroll
  for (int k = 0; k < 8; ++k) {
    if (k < 7)
      asm volatile("s_waitcnt vmcnt(4)" ::: "memory");
    else
      asm volatile("s_waitcnt vmcnt(0)" ::: "memory");
    __builtin_amdgcn_s_barrier();
    asm volatile("" ::: "memory");

    if (k + 2 < 8) stage(k + 2, (k + 2) % 3);

    const int buf = k % 3;
    bf16x8 a[2], b[8];
#pragma unroll
    for (int m = 0; m < 2; ++m)
      a[m] = *(const bf16x8*)&smem[aoff[m] + buf * 4096];
#pragma unroll
    for (int nt = 0; nt < 8; ++nt)
      b[nt] = *(const bf16x8*)&smem[boff[nt] + buf * 4096];

    __builtin_amdgcn_s_setprio(1);
#pragma unroll
    for (int m = 0; m < 2; ++m)
#pragma unroll
      for (int nt = 0; nt < 8; ++nt)
        acc[m][nt] = __builtin_amdgcn_mfma_f32_16x16x32_bf16(
            a[m], b[nt], acc[m][nt], 0, 0, 0);
    __builtin_amdgcn_s_setprio(0);
  }

#pragma unroll
  for (int m = 0; m < 2; ++m) {
#pragma unroll
    for (int nt = 0; nt < 8; ++nt) {
      const int co = (bn << 7) + (nt << 4) + lr;
      if (MODE == 0) {
#pragma unroll
        for (int reg = 0; reg < 4; ++reg) {
          const int sm = sm_base + (m << 4) + (lg << 2) + reg;
          out_b[((size_t)n * HW + s0 + sm) * 256 + co] = (__bf16)acc[m][nt][reg];
        }
      } else {
        const int sm = sm_base + (m << 4) + (lg << 2);
        float4 v4 = make_float4(acc[m][nt][0], acc[m][nt][1],
                                acc[m][nt][2], acc[m][nt][3]);
        *(float4*)&out_f[((size_t)(n * 256 + co)) * HW + s0 + sm] = v4;
      }
    }
  }
}

// ---------------------------------------------------------------------------
// fused_pre: pack_x (blocks 0..2047) + pack_all (blocks 2048..2815).
// ---------------------------------------------------------------------------
__global__ __launch_bounds__(256) void fused_pre_kernel(
    const float* __restrict__ x, __bf16* __restrict__ xp,
    const float* __restrict__ off_w, const float* __restrict__ off_b,
    const float* __restrict__ attn_w, const float* __restrict__ attn_b,
    const float* __restrict__ Wv, const float* __restrict__ Wo,
    __bf16* __restrict__ Wp, float* __restrict__ biasp,
    __bf16* __restrict__ zbuf, __bf16* __restrict__ Wvb,
    __bf16* __restrict__ Wob)
{
  const int b = blockIdx.x;
  const int tid = threadIdx.x;
  __shared__ float tile[64][65];

  if (b < 2048) {
    const int c0 = (b & 3) << 6;
    const int y  = (b >> 2) & 63;
    const int n  = b >> 8;
    const int tx = tid & 63, tg = tid >> 6;
#pragma unroll
    for (int i = 0; i < 16; ++i) {
      int cl = tg + (i << 2);
      tile[cl][tx] = x[((size_t)(n * C_ + c0 + cl) * H_ + y) * W_ + tx];
    }
    __syncthreads();
#pragma unroll
    for (int i = 0; i < 16; ++i) {
      int xl = tg + (i << 2);
      xp[((size_t)(n * HW) + y * W_ + xl) * C_ + c0 + tx] = (__bf16)tile[tx][xl];
    }
  } else {
    const int bb = b - 2048;
    const int c = tid;
    if (bb < 256) {
      const int co = bb;
      if (co == 0) {
        *(uint4*)&zbuf[(size_t)c * 8] = make_uint4(0u, 0u, 0u, 0u);
      }
      const float* base = nullptr;
      if (co < OFFCH)      base = off_w  + ((size_t)co * C_ + c) * 9;
      else if (co < 216)   base = attn_w + ((size_t)(co - OFFCH) * C_ + c) * 9;
#pragma unroll
      for (int t = 0; t < 9; ++t) {
        float w = base ? base[t] : 0.f;
        Wp[(size_t)co * KTOT + t * C_ + c] = (__bf16)w;
      }
      if (c == 0) {
        float bv = 0.f;
        if (co < OFFCH) bv = off_b[co];
        else if (co < 216) bv = attn_b[co - OFFCH];
        biasp[co] = bv;
      }
    } else if (bb < 512) {
      const int i = (bb - 256) * 256 + c;
      Wvb[i] = (__bf16)Wv[i];
    } else {
      const int i = (bb - 512) * 256 + c;
      Wob[i] = (__bf16)Wo[i];
    }
  }
}

// ---------------------------------------------------------------------------
// fused_cv: conv (bn 0..1) co-dispatched with vproj gemm (bn 2..3).
// ---------------------------------------------------------------------------
__global__ __launch_bounds__(256) void fused_cv_kernel(
    const __bf16* __restrict__ xp, const __bf16* __restrict__ Wp,
    const float* __restrict__ biasp, const __bf16* __restrict__ zbuf,
    __bf16* __restrict__ P2, const __bf16* __restrict__ Wvb,
    __bf16* __restrict__ vtb)
{
  __shared__ __align__(16) __bf16 smem[16896 + 12288];
  const int bn = blockIdx.y;
  if (bn < 2)
    conv_body(smem, xp, Wp, biasp, zbuf, P2, blockIdx.x, bn, blockIdx.z,
              threadIdx.x);
  else
    gemm_body<0>(smem, xp, Wvb, vtb, nullptr, blockIdx.x, bn - 2, blockIdx.z,
                 threadIdx.x);
}

// ---------------------------------------------------------------------------
// wo projection (standalone; depends on sample output).
// ---------------------------------------------------------------------------
__global__ __launch_bounds__(256) void wo_kernel(
    const __bf16* __restrict__ comb, const __bf16* __restrict__ Wob,
    float* __restrict__ out)
{
  __shared__ __align__(16) __bf16 smem[24576];
  gemm_body<1>(smem, comb, Wob, nullptr, out, blockIdx.x, blockIdx.y,
               blockIdx.z, threadIdx.x);
}

// ---------------------------------------------------------------------------
// Deformable sampling R33 (measured-best): 8 query rows per block at 1024
// threads. Window rows yb-3..yb+11 (15 rows, 60 KB) staged via 64 wave-slots
// (slot = step*16+wv -> row r=slot>>2, x-quarter q=slot&3; wave-uniform).
// Lanes/point = 2 (x 16 ch, bracketed optimum). Exact global fallback.
// ---------------------------------------------------------------------------
__global__ __launch_bounds__(1024) void sample_kernel(
    const __bf16* __restrict__ vtb, const __bf16* __restrict__ P2,
    __bf16* __restrict__ comb)
{
  const int b  = blockIdx.x;           // (n*8 + h)*8 + y8
  const int y8 = b & 7;
  const int h  = (b >> 3) & 7;
  const int n  = b >> 6;
  const int yb = y8 << 3;              // query rows yb..yb+7
  const int tid = threadIdx.x;
  const int cg  = tid & 1;             // 16-channel half
  const int pt  = tid >> 1;            // 0..511
  const int yloc = pt >> 6, xq = pt & 63;
  const int y = yb + yloc;
  const int wv = tid >> 6;             // 0..15

  __shared__ __align__(16) __bf16 vsl[15 * 64 * 32];   // rows yb-3..yb+11, 60 KB

  // ---- stage 15 window rows: 64 wave-slots over 4 steps ----
  const int lane = tid & 63;
  const int cs = tid & 3;
  const __bf16* vhead = vtb + ((size_t)n * HW) * 256 + (h << 5) + (cs << 3);
#pragma unroll
  for (int step = 0; step < 4; ++step) {
    int slot = step * 16 + wv;         // wave-uniform
    int r = slot >> 2, q = slot & 3;
    if (r < 15) {
      int yy = yb - 3 + r;
      if ((unsigned)yy < (unsigned)H_) {
        int xs = (q << 4) + (lane >> 2);
        gload_lds16(vhead + ((size_t)yy * W_ + xs) * 256,
                    &vsl[(r * 64 + (q << 4)) * 32]);
      }
    }
  }

  const __bf16* prow = P2 + ((size_t)n * HW + y * 64 + xq) * 256 + (h << 5);
  bf16x8 p0 = *(const bf16x8*)(prow);
  bf16x8 p1 = *(const bf16x8*)(prow + 8);
  bf16x8 p2 = *(const bf16x8*)(prow + 16);
  bf16x4 p3 = *(const bf16x4*)(prow + 24);

  __syncthreads();                               // drains vmcnt (gload_lds)

  float acc[16];
#pragma unroll
  for (int j = 0; j < 16; ++j) acc[j] = 0.f;

  const __bf16* vbase = vtb + ((size_t)n * HW) * 256 + (h << 5) + (cg << 4);

#pragma unroll
  for (int k = 0; k < K2; ++k) {
    float offx, offy, a;
    if (k < 4)      { offx = (float)p0[2 * k];       offy = (float)p0[2 * k + 1]; }
    else if (k < 8) { offx = (float)p1[2 * (k - 4)]; offy = (float)p1[2 * (k - 4) + 1]; }
    else            { offx = (float)p2[0];           offy = (float)p2[1]; }
    if (k < 6)      a = (float)p2[2 + k];
    else            a = (float)p3[k - 6];

    const float xpf = (float)xq + offx * (63.f / 64.f);
    const float ypf = (float)y  + offy * (63.f / 64.f);
    const float fx0 = floorf(xpf), fy0 = floorf(ypf);
    const int ix0 = (int)fx0, iy0 = (int)fy0;
    const float wx1 = xpf - fx0, wx0 = 1.f - wx1;
    const float wy1 = ypf - fy0, wy0 = 1.f - wy1;

#pragma unroll
    for (int cy = 0; cy < 2; ++cy) {
      const int yi = iy0 + cy;
      if ((unsigned)yi >= (unsigned)H_) continue;
      const float wy = cy ? wy1 : wy0;
      const int ridx = yi - (yb - 3);
#pragma unroll
      for (int cx = 0; cx < 2; ++cx) {
        const int xi = ix0 + cx;
        if ((unsigned)xi >= (unsigned)W_) continue;
        const float cw = a * wy * (cx ? wx1 : wx0);
        bf16x8 v0, v1;
        if ((unsigned)ridx < 15u) {              // in-window: LDS
          const __bf16* lp = &vsl[(ridx * 64 + xi) * 32 + (cg << 4)];
          v0 = *(const bf16x8*)lp;
          v1 = *(const bf16x8*)(lp + 8);
        } else {                                 // rare escape: global
          const __bf16* gp = vbase + (size_t)(yi * W_ + xi) * 256;
          v0 = *(const bf16x8*)gp;
          v1 = *(const bf16x8*)(gp + 8);
        }
#pragma unroll
        for (int j = 0; j < 8; ++j) acc[j] = fmaf(cw, (float)v0[j], acc[j]);
#pragma unroll
        for (int j = 0; j < 8; ++j)
          acc[8 + j] = fmaf(cw, (float)v1[j], acc[8 + j]);
      }
    }
  }

  bf16x8 r0, r1;
#pragma unroll
  for (int j = 0; j < 8; ++j) { r0[j] = (__bf16)acc[j]; r1[j] = (__bf16)acc[8 + j]; }
  __bf16* crow = comb + ((size_t)n * HW + y * 64 + xq) * 256 + (h << 5) + (cg << 4);
  *(bf16x8*)crow = r0;
  *(bf16x8*)(crow + 8) = r1;
}

// ---------------------------------------------------------------------------
extern "C" void kernel_launch(void* const* d_in, const int* in_sizes, int n_in,
                              void* d_out, int out_size, void* d_ws,
                              size_t ws_size, hipStream_t stream)
{
  const float* x      = (const float*)d_in[0];
  // d_in[1] = Wq, d_in[2] = Wk : dead code (q,k unused in reference)
  const float* Wv     = (const float*)d_in[3];
  const float* off_w  = (const float*)d_in[4];
  const float* off_b  = (const float*)d_in[5];
  const float* attn_w = (const float*)d_in[6];
  const float* attn_b = (const float*)d_in[7];
  const float* Wo     = (const float*)d_in[8];
  float* out = (float*)d_out;

  __bf16* vtb   = (__bf16*)d_ws;                         // 16.78 MB
  __bf16* xp    = vtb + (size_t)N_ * HW * OUT_;          // 16.78 MB
  __bf16* comb  = xp + (size_t)N_ * HW * C_;             // 16.78 MB
  __bf16* P2    = comb + (size_t)N_ * HW * OUT_;         // 16.78 MB (head-packed)
  __bf16* Wp    = P2 + (size_t)N_ * HW * 256;            //  1.18 MB (256 rows)
  __bf16* Wvb   = Wp + (size_t)WPROWS * KTOT;            //  128 KB
  __bf16* Wob   = Wvb + (size_t)OUT_ * C_;               //  128 KB
  __bf16* zbuf  = Wob + (size_t)OUT_ * OUT_;             //  4 KB zero page
  float*  biasp = (float*)(zbuf + 2048);                 //  1 KB

  fused_pre_kernel<<<dim3(2816), 256, 0, stream>>>(
      x, xp, off_w, off_b, attn_w, attn_b, Wv, Wo, Wp, biasp, zbuf, Wvb, Wob);
  fused_cv_kernel<<<dim3(32, 4, N_), 256, 0, stream>>>(xp, Wp, biasp, zbuf, P2,
                                                       Wvb, vtb);
  sample_kernel<<<dim3(N_ * HEADS * 8), 1024, 0, stream>>>(vtb, P2, comb);
  wo_kernel<<<dim3(32, 2, N_), 256, 0, stream>>>(comb, Wob, out);
}